// Round 1
// baseline (10683.491 us; speedup 1.0000x reference)
//
#include <hip/hip_runtime.h>
#include <hip/hip_bf16.h>

// ---------------------------------------------------------------------------
// Performer (FAVOR+) concentration model, fp32 correctness-first version.
// B=256, N=300, IN_DIM=1280, DIM=256, DEPTH=2, HEADS=4, DH=64, MF=266, FFH=1024
// ---------------------------------------------------------------------------

#define MF 266          // nb random features
#define NSEQ 300
#define DIMC 256
#define NORM_QK 0.3535533905932738f   // 64^-0.25
#define KEPS 1e-4f

// ---------------------------------------------------------------------------
// Generic fp32 GEMM: C[M,N] = epi(A[M,K] @ W[K,N] + bias [+ R])
// 128x128 tile, BK=8, 256 threads, 8x8 per-thread microtile.
// EPI: 0 = +bias ; 1 = +bias +residual ; 2 = gelu_tanh(+bias) ; 3 = plain
// Requires M%128==0, N%128==0, K%8==0 (true for all shapes used here).
// ---------------------------------------------------------------------------
template<int EPI>
__global__ __launch_bounds__(256) void gemm128(
    const float* __restrict__ A, const float* __restrict__ W,
    const float* __restrict__ bias, const float* __restrict__ R,
    float* __restrict__ C, int M, int N, int K)
{
  __shared__ float As[8][132];   // [k][m], +4 pad
  __shared__ float Bs[8][132];   // [k][n]
  const int tid = threadIdx.x;
  const int row0 = blockIdx.x * 128, col0 = blockIdx.y * 128;
  const int tx = tid & 15, ty = tid >> 4;
  const int a_k = tid & 7,  a_m = tid >> 3;    // A tile: 128 rows x 8 k
  const int b_n = tid & 127, b_k = tid >> 7;   // B tile: 8 k x 128 n
  float acc[8][8] = {};
  const float* Ap = A + (size_t)row0 * K;
  const float* Wp = W + col0;
  for (int k0 = 0; k0 < K; k0 += 8) {
#pragma unroll
    for (int i = 0; i < 4; i++)
      As[a_k][a_m + 32*i] = Ap[(size_t)(a_m + 32*i) * K + (k0 + a_k)];
#pragma unroll
    for (int i = 0; i < 4; i++)
      Bs[b_k + 2*i][b_n] = Wp[(size_t)(k0 + b_k + 2*i) * N + b_n];
    __syncthreads();
#pragma unroll
    for (int kk = 0; kk < 8; kk++) {
      const float4 a0 = *(const float4*)&As[kk][ty*8];
      const float4 a1 = *(const float4*)&As[kk][ty*8+4];
      const float4 b0 = *(const float4*)&Bs[kk][tx*8];
      const float4 b1 = *(const float4*)&Bs[kk][tx*8+4];
      const float av[8] = {a0.x,a0.y,a0.z,a0.w,a1.x,a1.y,a1.z,a1.w};
      const float bv[8] = {b0.x,b0.y,b0.z,b0.w,b1.x,b1.y,b1.z,b1.w};
#pragma unroll
      for (int i = 0; i < 8; i++)
#pragma unroll
        for (int j = 0; j < 8; j++)
          acc[i][j] += av[i] * bv[j];
    }
    __syncthreads();
  }
#pragma unroll
  for (int i = 0; i < 8; i++) {
    const size_t r = (size_t)(row0 + ty*8 + i) * N;
#pragma unroll
    for (int j = 0; j < 8; j++) {
      const int c = col0 + tx*8 + j;
      float vv = acc[i][j];
      if (EPI != 3) vv += bias[c];
      if (EPI == 1) vv += R[r + c];
      if (EPI == 2) {
        const float xx = vv;  // jax.nn.gelu default: tanh approximation
        vv = 0.5f * xx * (1.0f + tanhf(0.7978845608028654f * (xx + 0.044715f * xx * xx * xx)));
      }
      C[r + c] = vv;
    }
  }
}

// ---------------------------------------------------------------------------
// LayerNorm over last dim (256). One wave per row, 4 rows per block.
// ---------------------------------------------------------------------------
__global__ __launch_bounds__(256) void ln_kernel(
    const float* __restrict__ x, const float* __restrict__ g,
    const float* __restrict__ b, float* __restrict__ y)
{
  const int wid = threadIdx.x >> 6, lane = threadIdx.x & 63;
  const int row = blockIdx.x * 4 + wid;
  const float* xr = x + (size_t)row * DIMC;
  float v[4];
  float s = 0.f;
#pragma unroll
  for (int i = 0; i < 4; i++) { v[i] = xr[lane + 64*i]; s += v[i]; }
#pragma unroll
  for (int off = 32; off; off >>= 1) s += __shfl_xor(s, off);
  const float mu = s * (1.0f/256.0f);
  float var = 0.f;
#pragma unroll
  for (int i = 0; i < 4; i++) { const float d = v[i] - mu; var += d*d; }
#pragma unroll
  for (int off = 32; off; off >>= 1) var += __shfl_xor(var, off);
  const float rstd = rsqrtf(var * (1.0f/256.0f) + 1e-5f);
  float* yr = y + (size_t)row * DIMC;
#pragma unroll
  for (int i = 0; i < 4; i++) {
    const int c = lane + 64*i;
    yr[c] = (v[i] - mu) * rstd * g[c] + b[c];
  }
}

// ---------------------------------------------------------------------------
// FAVOR+ key-side: per (b,h) compute
//   stab   = max_{n,m} dd[n][m],  dd = (k*norm) @ proj^T
//   kp     = exp(dd - diag_k - stab) + eps        (ratio dropped: cancels)
//   ksum[m]   = sum_n kp[n][m]
//   ctx[m][d] = sum_n kp[n][m] * v[n][d]
// One block per bh (1024 blocks), 320 threads, lane-owns-m. k,v staged in LDS.
// ---------------------------------------------------------------------------
__global__ __launch_bounds__(320) void favor_ctx_kernel(
    const float* __restrict__ Kp, const float* __restrict__ Vp,
    const float* __restrict__ proj,
    float* __restrict__ ctx_out, float* __restrict__ ksum_out)
{
  __shared__ float kn_s[NSEQ][64];
  __shared__ float v_s[NSEQ][64];
  __shared__ float diag_s[NSEQ];
  __shared__ float red_s[5];
  const int tid = threadIdx.x;
  const int bh = blockIdx.x;
  const int b = bh >> 2, h = bh & 3;
  {
    const int d = tid & 63, nr = tid >> 6;   // 5 rows per pass
    const float* Kb = Kp + (size_t)b * NSEQ * DIMC + h * 64;
    const float* Vb = Vp + (size_t)b * NSEQ * DIMC + h * 64;
    for (int n = nr; n < NSEQ; n += 5) {
      kn_s[n][d] = Kb[(size_t)n * DIMC + d] * NORM_QK;
      v_s[n][d]  = Vb[(size_t)n * DIMC + d];
    }
  }
  __syncthreads();
  for (int n = tid; n < NSEQ; n += 320) {
    float s = 0.f;
    const float4* kr = (const float4*)kn_s[n];
#pragma unroll
    for (int c2 = 0; c2 < 16; c2++) {
      const float4 kv = kr[c2];
      s += kv.x*kv.x + kv.y*kv.y + kv.z*kv.z + kv.w*kv.w;
    }
    diag_s[n] = 0.5f * s;
  }
  const int m = tid;
  const bool act = (m < MF);
  float pr[64];
  {
    const float4* pp = (const float4*)(proj + (size_t)(act ? m : 0) * 64);
#pragma unroll
    for (int c2 = 0; c2 < 16; c2++) {
      const float4 t = pp[c2];
      pr[4*c2] = t.x; pr[4*c2+1] = t.y; pr[4*c2+2] = t.z; pr[4*c2+3] = t.w;
    }
  }
  // pass 1: global max of dd
  float mx = -3.0e38f;
  for (int n = 0; n < NSEQ; n++) {
    const float4* kr = (const float4*)kn_s[n];
    float s = 0.f;
#pragma unroll
    for (int c2 = 0; c2 < 16; c2++) {
      const float4 kv = kr[c2];
      s += kv.x*pr[4*c2] + kv.y*pr[4*c2+1] + kv.z*pr[4*c2+2] + kv.w*pr[4*c2+3];
    }
    mx = fmaxf(mx, s);
  }
  if (!act) mx = -3.0e38f;
#pragma unroll
  for (int off = 32; off; off >>= 1) mx = fmaxf(mx, __shfl_xor(mx, off));
  if ((tid & 63) == 0) red_s[tid >> 6] = mx;
  __syncthreads();
  const float stab = fmaxf(fmaxf(fmaxf(red_s[0], red_s[1]), fmaxf(red_s[2], red_s[3])), red_s[4]);
  // pass 2: kp, ksum, ctx
  float ctx[64];
#pragma unroll
  for (int i = 0; i < 64; i++) ctx[i] = 0.f;
  float ks = 0.f;
  for (int n = 0; n < NSEQ; n++) {
    const float4* kr = (const float4*)kn_s[n];
    float s = 0.f;
#pragma unroll
    for (int c2 = 0; c2 < 16; c2++) {
      const float4 kv = kr[c2];
      s += kv.x*pr[4*c2] + kv.y*pr[4*c2+1] + kv.z*pr[4*c2+2] + kv.w*pr[4*c2+3];
    }
    const float kp = __expf(s - diag_s[n] - stab) + KEPS;
    ks += kp;
    const float4* vr = (const float4*)v_s[n];
#pragma unroll
    for (int c2 = 0; c2 < 16; c2++) {
      const float4 vv = vr[c2];
      ctx[4*c2]   += kp * vv.x; ctx[4*c2+1] += kp * vv.y;
      ctx[4*c2+2] += kp * vv.z; ctx[4*c2+3] += kp * vv.w;
    }
  }
  if (act) {
    float* co = ctx_out + ((size_t)bh * MF + m) * 64;
#pragma unroll
    for (int i = 0; i < 64; i++) co[i] = ctx[i];
    ksum_out[(size_t)bh * MF + m] = ks;
  }
}

// ---------------------------------------------------------------------------
// FAVOR+ query-side: per (b,h):
//   qp[n][m] = exp(dd - diag_q[n] - rowmax_n(dd)) + eps
//   o[n][d]  = (qp[n] . ctx[:,d]) / (qp[n] . ksum)
// One block per bh, 256 threads = 4 independent waves, 8 query rows per wave
// iteration. Per-wave LDS buffers; same-wave LDS ops are in-order (no barriers
// needed inside the loop).
// ---------------------------------------------------------------------------
__global__ __launch_bounds__(256) void favor_out_kernel(
    const float* __restrict__ Qp, const float* __restrict__ proj,
    const float* __restrict__ ctx_in, const float* __restrict__ ksum_in,
    float* __restrict__ Op)
{
  __shared__ float proj_s[MF][68];                 // 72,352 B
  __shared__ __hip_bfloat16 ctxT_s[64][272];       // 34,816 B  (ctx transposed)
  __shared__ float ksum_s[MF];                     //  1,064 B
  __shared__ float qrow_s[4][8][68];               //  8,704 B
  __shared__ float qp_s[4][8][272];                // 34,816 B   total ~152 KB
  const int tid = threadIdx.x;
  const int bh = blockIdx.x;
  const int b = bh >> 2, h = bh & 3;
  const int w = tid >> 6, lane = tid & 63;

  for (int idx = tid; idx < MF * 64; idx += 256) {
    const int mm = idx >> 6, d = idx & 63;
    proj_s[mm][d] = proj[idx];
  }
  const float* cb = ctx_in + (size_t)bh * MF * 64;
  for (int idx = tid; idx < MF * 64; idx += 256) {
    const int mm = idx >> 6, d = idx & 63;
    ctxT_s[d][mm] = __float2bfloat16(cb[idx]);
  }
  if (tid < 64) {  // zero pad columns (read by the 4-wide combine at m0=264)
    ctxT_s[tid][266] = __float2bfloat16(0.f);
    ctxT_s[tid][267] = __float2bfloat16(0.f);
  }
  for (int idx = tid; idx < MF; idx += 256)
    ksum_s[idx] = ksum_in[(size_t)bh * MF + idx];
  {
    float* qz = &qp_s[0][0][0];
    for (int idx = tid; idx < 4*8*272; idx += 256) qz[idx] = 0.f;  // pad m>=266 stays 0
  }
  __syncthreads();

  float ks_r[5];
#pragma unroll
  for (int mb = 0; mb < 5; mb++) {
    const int mm = mb*64 + lane;
    ks_r[mb] = (mm < MF) ? ksum_s[mm] : 0.f;
  }

  const float* Qb = Qp + (size_t)b * NSEQ * DIMC + h * 64;
  float* Ob = Op + (size_t)b * NSEQ * DIMC + h * 64;

  for (int g = w; g < 38; g += 4) {          // groups of 8 rows; 38*8 >= 300
    const int n0 = g * 8;
    // stage 8 q rows (normalized) + diag via shuffle reduce
    float diag[8];
#pragma unroll
    for (int j = 0; j < 8; j++) {
      const int n = n0 + j;
      const float qv = (n < NSEQ) ? Qb[(size_t)n * DIMC + lane] * NORM_QK : 0.f;
      qrow_s[w][j][lane] = qv;
      float sq = qv * qv;
#pragma unroll
      for (int off = 32; off; off >>= 1) sq += __shfl_xor(sq, off);
      diag[j] = 0.5f * sq;
    }
    // dd[mb][j] = qn[j] . proj[mb*64+lane]
    float dd[5][8];
#pragma unroll
    for (int mb = 0; mb < 5; mb++)
#pragma unroll
      for (int j = 0; j < 8; j++) dd[mb][j] = 0.f;
    for (int d0 = 0; d0 < 64; d0 += 4) {
      float4 pv[5];
#pragma unroll
      for (int mb = 0; mb < 5; mb++) {
        const int mm = mb*64 + lane;
        const int mc = mm < MF ? mm : MF - 1;
        pv[mb] = *(const float4*)&proj_s[mc][d0];
      }
#pragma unroll
      for (int j = 0; j < 8; j++) {
        const float4 qv = *(const float4*)&qrow_s[w][j][d0];
#pragma unroll
        for (int mb = 0; mb < 5; mb++)
          dd[mb][j] += qv.x*pv[mb].x + qv.y*pv[mb].y + qv.z*pv[mb].z + qv.w*pv[mb].w;
      }
    }
    // per-row max, qp = exp(dd - diag - max) + eps, denom, store qp to LDS
    float dinv[8];
#pragma unroll
    for (int j = 0; j < 8; j++) {
      float mxx = -3.0e38f;
#pragma unroll
      for (int mb = 0; mb < 5; mb++) {
        const int mm = mb*64 + lane;
        if (mm < MF) mxx = fmaxf(mxx, dd[mb][j]);
      }
#pragma unroll
      for (int off = 32; off; off >>= 1) mxx = fmaxf(mxx, __shfl_xor(mxx, off));
      float dpart = 0.f;
#pragma unroll
      for (int mb = 0; mb < 5; mb++) {
        const int mm = mb*64 + lane;
        float qpv = 0.f;
        if (mm < MF) qpv = __expf(dd[mb][j] - diag[j] - mxx) + KEPS;
        dd[mb][j] = qpv;
        dpart += qpv * ks_r[mb];
      }
#pragma unroll
      for (int off = 32; off; off >>= 1) dpart += __shfl_xor(dpart, off);
      dinv[j] = 1.0f / dpart;
#pragma unroll
      for (int mb = 0; mb < 5; mb++) {
        const int mm = mb*64 + lane;
        if (mm < MF) qp_s[w][j][mm] = dd[mb][j];
      }
    }
    // combine: o[j][lane] = dinv[j] * sum_m qp[j][m] * ctxT[lane][m]
    float acc[8] = {0.f,0.f,0.f,0.f,0.f,0.f,0.f,0.f};
    const __hip_bfloat162* crow = (const __hip_bfloat162*)&ctxT_s[lane][0];
    for (int m0 = 0; m0 < 268; m0 += 4) {
      const float2 c01 = __bfloat1622float2(crow[m0 >> 1]);
      const float2 c23 = __bfloat1622float2(crow[(m0 >> 1) + 1]);
#pragma unroll
      for (int j = 0; j < 8; j++) {
        const float4 qv = *(const float4*)&qp_s[w][j][m0];   // broadcast read
        acc[j] += qv.x*c01.x + qv.y*c01.y + qv.z*c23.x + qv.w*c23.y;
      }
    }
#pragma unroll
    for (int j = 0; j < 8; j++) {
      const int n = n0 + j;
      if (n < NSEQ) Ob[(size_t)n * DIMC + lane] = acc[j] * dinv[j];
    }
  }
}

// ---------------------------------------------------------------------------
// Mean-pool over N, LayerNorm, 256->128 ReLU, 128->1 sigmoid. Block per batch.
// ---------------------------------------------------------------------------
__global__ __launch_bounds__(256) void head_kernel(
    const float* __restrict__ h, const float* __restrict__ hg,
    const float* __restrict__ hb, const float* __restrict__ wh1,
    const float* __restrict__ bh1, const float* __restrict__ wh2,
    const float* __restrict__ bh2, float* __restrict__ out)
{
  __shared__ float z_s[256];
  __shared__ float hid_s[128];
  __shared__ float red_s[4];
  const int b = blockIdx.x, tid = threadIdx.x;
  const float* hb_ = h + (size_t)b * NSEQ * DIMC;
  float s = 0.f;
  for (int n = 0; n < NSEQ; n++) s += hb_[(size_t)n * DIMC + tid];
  s *= (1.0f / 300.0f);
  float t1 = s;
#pragma unroll
  for (int off = 32; off; off >>= 1) t1 += __shfl_xor(t1, off);
  if ((tid & 63) == 0) red_s[tid >> 6] = t1;
  __syncthreads();
  const float mu = (red_s[0] + red_s[1] + red_s[2] + red_s[3]) * (1.0f/256.0f);
  __syncthreads();
  const float d = s - mu;
  float vv = d * d;
#pragma unroll
  for (int off = 32; off; off >>= 1) vv += __shfl_xor(vv, off);
  if ((tid & 63) == 0) red_s[tid >> 6] = vv;
  __syncthreads();
  const float var = (red_s[0] + red_s[1] + red_s[2] + red_s[3]) * (1.0f/256.0f);
  z_s[tid] = d * rsqrtf(var + 1e-5f) * hg[tid] + hb[tid];
  __syncthreads();
  if (tid < 128) {
    float acc = bh1[tid];
    for (int dd = 0; dd < 256; dd++) acc += z_s[dd] * wh1[dd * 128 + tid];
    hid_s[tid] = fmaxf(acc, 0.f);
  }
  __syncthreads();
  if (tid < 64) {
    float acc = hid_s[tid] * wh2[tid] + hid_s[tid + 64] * wh2[tid + 64];
#pragma unroll
    for (int off = 32; off; off >>= 1) acc += __shfl_xor(acc, off);
    if (tid == 0) {
      const float val = acc + bh2[0];
      out[b] = 1.0f / (1.0f + __expf(-val));
    }
  }
}

// ---------------------------------------------------------------------------
extern "C" void kernel_launch(void* const* d_in, const int* in_sizes, int n_in,
                              void* d_out, int out_size, void* d_ws, size_t ws_size,
                              hipStream_t stream) {
  const float* x    = (const float*)d_in[0];
  const float* w_in = (const float*)d_in[1];
  const float* b_in = (const float*)d_in[2];
  const float* proj = (const float*)d_in[3];
  const float* ln1g = (const float*)d_in[4];
  const float* ln1b = (const float*)d_in[5];
  const float* wq   = (const float*)d_in[6];
  const float* wk   = (const float*)d_in[7];
  const float* wv   = (const float*)d_in[8];
  const float* wo   = (const float*)d_in[9];
  const float* bo   = (const float*)d_in[10];
  const float* ln2g = (const float*)d_in[11];
  const float* ln2b = (const float*)d_in[12];
  const float* w1   = (const float*)d_in[13];
  const float* b1   = (const float*)d_in[14];
  const float* w2   = (const float*)d_in[15];
  const float* b2   = (const float*)d_in[16];
  const float* hg   = (const float*)d_in[17];
  const float* hbp  = (const float*)d_in[18];
  const float* wh1  = (const float*)d_in[19];
  const float* bh1  = (const float*)d_in[20];
  const float* wh2  = (const float*)d_in[21];
  const float* bh2  = (const float*)d_in[22];

  float* ws = (float*)d_ws;
  const size_t SE = (size_t)76800 * 256;   // 19.66M floats per [B*N, DIM] buffer
  float* h  = ws;
  float* y  = ws + SE;        // also hosts ctx+ksum (dead interval of y)
  float* q  = ws + 2*SE;      // also hosts FFN hidden chunk (dead interval of q)
  float* k  = ws + 3*SE;
  float* v  = ws + 4*SE;
  float* o  = ws + 5*SE;
  float* t  = q;
  float* ctx  = y;                              // 1024*266*64 floats
  float* ksum = y + (size_t)1024 * MF * 64;     // 1024*266 floats

  const dim3 blk(256);
  // h = x @ w_in + b_in
  gemm128<0><<<dim3(600, 2), blk, 0, stream>>>(x, w_in, b_in, nullptr, h, 76800, 256, 1280);

  for (int l = 0; l < 2; l++) {
    const float* projL = proj + (size_t)l * MF * 64;
    ln_kernel<<<19200, 256, 0, stream>>>(h, ln1g + l*256, ln1b + l*256, y);
    gemm128<3><<<dim3(600, 2), blk, 0, stream>>>(y, wq + (size_t)l*65536, nullptr, nullptr, q, 76800, 256, 256);
    gemm128<3><<<dim3(600, 2), blk, 0, stream>>>(y, wk + (size_t)l*65536, nullptr, nullptr, k, 76800, 256, 256);
    gemm128<3><<<dim3(600, 2), blk, 0, stream>>>(y, wv + (size_t)l*65536, nullptr, nullptr, v, 76800, 256, 256);
    favor_ctx_kernel<<<1024, 320, 0, stream>>>(k, v, projL, ctx, ksum);
    favor_out_kernel<<<1024, 256, 0, stream>>>(q, projL, ctx, ksum, o);
    // h = h + o @ wo + bo
    gemm128<1><<<dim3(600, 2), blk, 0, stream>>>(o, wo + (size_t)l*65536, bo + l*256, h, h, 76800, 256, 256);
    ln_kernel<<<19200, 256, 0, stream>>>(h, ln2g + l*256, ln2b + l*256, y);
    // FFN, chunked over rows so hidden buffer fits the aliased q region
    for (int rc = 0; rc < 4; rc++) {
      const float* yc = y + (size_t)rc * 19200 * 256;
      float* hc = h + (size_t)rc * 19200 * 256;
      gemm128<2><<<dim3(150, 8), blk, 0, stream>>>(yc, w1 + (size_t)l*262144, b1 + l*1024, nullptr, t, 19200, 1024, 256);
      gemm128<1><<<dim3(150, 2), blk, 0, stream>>>(t, w2 + (size_t)l*262144, b2 + l*256, hc, hc, 19200, 256, 1024);
    }
  }
  head_kernel<<<256, 256, 0, stream>>>(h, hg, hbp, wh1, bh1, wh2, bh2, (float*)d_out);
}

// Round 2
// 5490.957 us; speedup vs baseline: 1.9457x; 1.9457x over previous
//
#include <hip/hip_runtime.h>
#include <hip/hip_bf16.h>

// ---------------------------------------------------------------------------
// Performer (FAVOR+) concentration model — round 2: bf16 MFMA GEMMs +
// occupancy fixes for the favor kernels.
// B=256, N=300, IN_DIM=1280, DIM=256, DEPTH=2, HEADS=4, DH=64, MF=266, FFH=1024
// ---------------------------------------------------------------------------

#define MF 266
#define NSEQ 300
#define DIMC 256
#define NORM_QK 0.3535533905932738f   // 64^-0.25
#define KEPS 1e-4f

typedef __attribute__((ext_vector_type(8))) short bf16x8;
typedef __attribute__((ext_vector_type(4))) float f32x4;

__device__ __forceinline__ float bfbits2f(unsigned short u) {
  return __uint_as_float(((unsigned int)u) << 16);
}

// ---------------------------------------------------------------------------
// bf16 MFMA GEMM: C[M,N] = epi(A[M,K]bf16 @ BT[N,K]bf16^T + bias [+R])
// 128x128 tile, BK=32, 256 threads = 4 waves (2x2), each wave 64x64 via
// 4x4 grid of 16x16x32 MFMAs. Requires M%128==0, N%128==0, K%32==0.
// EPI: 0=+bias ; 1=+bias+residual ; 2=gelu(+bias) ; 3=plain
// OUTBF: 1 -> write bf16 to Cb, else fp32 to Cf.
// ---------------------------------------------------------------------------
template<int EPI, int OUTBF>
__global__ __launch_bounds__(256) void gemm_mfma(
    const ushort* __restrict__ A, const ushort* __restrict__ BT,
    const float* __restrict__ bias, const float* __restrict__ R,
    float* __restrict__ Cf, __hip_bfloat16* __restrict__ Cb,
    int M, int N, int K)
{
  __shared__ ushort As[128][32];   // 8 KB
  __shared__ ushort Bs[128][32];   // 8 KB
  const int tid = threadIdx.x;
  const int row0 = blockIdx.x << 7, col0 = blockIdx.y << 7;
  const int w = tid >> 6, lane = tid & 63;
  const int wm = (w >> 1) << 6, wn = (w & 1) << 6;
  const int r = lane & 15, quad = lane >> 4;
  const int sr = tid >> 2, sc = (tid & 3) << 3;   // staging: row, col (ushorts)
  f32x4 acc[4][4];
#pragma unroll
  for (int i = 0; i < 4; i++)
#pragma unroll
    for (int j = 0; j < 4; j++) acc[i][j] = (f32x4){0.f, 0.f, 0.f, 0.f};
  const ushort* ap0 = A + (size_t)(row0 + sr) * K + sc;
  const ushort* ap1 = A + (size_t)(row0 + sr + 64) * K + sc;
  const ushort* bp0 = BT + (size_t)(col0 + sr) * K + sc;
  const ushort* bp1 = BT + (size_t)(col0 + sr + 64) * K + sc;
  for (int k0 = 0; k0 < K; k0 += 32) {
    *(uint4*)&As[sr][sc]    = *(const uint4*)(ap0 + k0);
    *(uint4*)&As[sr+64][sc] = *(const uint4*)(ap1 + k0);
    *(uint4*)&Bs[sr][sc]    = *(const uint4*)(bp0 + k0);
    *(uint4*)&Bs[sr+64][sc] = *(const uint4*)(bp1 + k0);
    __syncthreads();
    bf16x8 af[4], bfv[4];
#pragma unroll
    for (int i = 0; i < 4; i++) af[i]  = *(const bf16x8*)&As[wm + i*16 + r][quad << 3];
#pragma unroll
    for (int i = 0; i < 4; i++) bfv[i] = *(const bf16x8*)&Bs[wn + i*16 + r][quad << 3];
#pragma unroll
    for (int mi = 0; mi < 4; mi++)
#pragma unroll
      for (int ni = 0; ni < 4; ni++)
        acc[mi][ni] = __builtin_amdgcn_mfma_f32_16x16x32_bf16(af[mi], bfv[ni], acc[mi][ni], 0, 0, 0);
    __syncthreads();
  }
  // epilogue: C/D layout col=lane&15, row=quad*4+reg  [m89-verified]
#pragma unroll
  for (int mi = 0; mi < 4; mi++) {
    const int rowb = row0 + wm + mi*16 + (quad << 2);
#pragma unroll
    for (int ni = 0; ni < 4; ni++) {
      const int col = col0 + wn + ni*16 + r;
      const float bv = (EPI == 3) ? 0.f : bias[col];
#pragma unroll
      for (int j = 0; j < 4; j++) {
        const size_t off = (size_t)(rowb + j) * N + col;
        float vv = acc[mi][ni][j] + bv;
        if (EPI == 1) vv += R[off];
        if (EPI == 2) {
          const float xx = vv;
          vv = 0.5f * xx * (1.0f + tanhf(0.7978845608028654f * (xx + 0.044715f * xx * xx * xx)));
        }
        if (OUTBF) Cb[off] = __float2bfloat16(vv);
        else       Cf[off] = vv;
      }
    }
  }
}

// ---------------------------------------------------------------------------
// fp32 -> bf16 flat cast (x), float4 vectorized.
// ---------------------------------------------------------------------------
__global__ __launch_bounds__(256) void cast_bf16_kernel(
    const float* __restrict__ in, __hip_bfloat16* __restrict__ out, int n4)
{
  const int i = blockIdx.x * 256 + threadIdx.x;
  if (i >= n4) return;
  const float4 v = ((const float4*)in)[i];
  union { ushort4 u; __hip_bfloat16 b[4]; } rr;
  rr.b[0] = __float2bfloat16(v.x); rr.b[1] = __float2bfloat16(v.y);
  rr.b[2] = __float2bfloat16(v.z); rr.b[3] = __float2bfloat16(v.w);
  ((ushort4*)out)[i] = rr.u;
}

// ---------------------------------------------------------------------------
// fp32 [R][C] -> bf16 [C][R] transpose-cast, 32x32 tiles. R,C % 32 == 0.
// ---------------------------------------------------------------------------
__global__ __launch_bounds__(256) void tcast_kernel(
    const float* __restrict__ in, __hip_bfloat16* __restrict__ out, int R, int C)
{
  __shared__ float t[32][33];
  const int c0 = blockIdx.x * 32, r0 = blockIdx.y * 32;
  const int tx = threadIdx.x & 31, ty = threadIdx.x >> 5;
#pragma unroll
  for (int i = 0; i < 32; i += 8)
    t[ty + i][tx] = in[(size_t)(r0 + ty + i) * C + c0 + tx];
  __syncthreads();
#pragma unroll
  for (int i = 0; i < 32; i += 8)
    out[(size_t)(c0 + ty + i) * R + r0 + tx] = __float2bfloat16(t[tx][ty + i]);
}

// ---------------------------------------------------------------------------
// LayerNorm over last dim (256), bf16 output. One wave per row, 4 rows/block.
// ---------------------------------------------------------------------------
__global__ __launch_bounds__(256) void ln_kernel(
    const float* __restrict__ x, const float* __restrict__ g,
    const float* __restrict__ b, __hip_bfloat16* __restrict__ y)
{
  const int wid = threadIdx.x >> 6, lane = threadIdx.x & 63;
  const int row = blockIdx.x * 4 + wid;
  const float* xr = x + (size_t)row * DIMC;
  float v[4];
  float s = 0.f;
#pragma unroll
  for (int i = 0; i < 4; i++) { v[i] = xr[lane + 64*i]; s += v[i]; }
#pragma unroll
  for (int off = 32; off; off >>= 1) s += __shfl_xor(s, off);
  const float mu = s * (1.0f/256.0f);
  float var = 0.f;
#pragma unroll
  for (int i = 0; i < 4; i++) { const float d = v[i] - mu; var += d*d; }
#pragma unroll
  for (int off = 32; off; off >>= 1) var += __shfl_xor(var, off);
  const float rstd = rsqrtf(var * (1.0f/256.0f) + 1e-5f);
  __hip_bfloat16* yr = y + (size_t)row * DIMC;
#pragma unroll
  for (int i = 0; i < 4; i++) {
    const int c = lane + 64*i;
    yr[c] = __float2bfloat16((v[i] - mu) * rstd * g[c] + b[c]);
  }
}

// ---------------------------------------------------------------------------
// FAVOR+ key-side. One block per (b,h), 320 threads, lane-owns-m.
// kn staged in LDS (78 KB -> 2 blocks/CU); v read from global (wave-broadcast,
// L1/L2-served). Two passes: global max, then kp/ksum/ctx.
// ---------------------------------------------------------------------------
__global__ __launch_bounds__(320) void favor_ctx_kernel(
    const float* __restrict__ Kp, const float* __restrict__ Vp,
    const float* __restrict__ proj,
    float* __restrict__ ctx_out, float* __restrict__ ksum_out)
{
  __shared__ float kn_s[NSEQ][64];   // 76,800 B
  __shared__ float diag_s[NSEQ];
  __shared__ float red_s[5];
  const int tid = threadIdx.x;
  const int bh = blockIdx.x;
  const int b = bh >> 2, h = bh & 3;
  const float* Vb = Vp + (size_t)b * NSEQ * DIMC + h * 64;
  {
    const int d = tid & 63, nr = tid >> 6;
    const float* Kb = Kp + (size_t)b * NSEQ * DIMC + h * 64;
    for (int n = nr; n < NSEQ; n += 5)
      kn_s[n][d] = Kb[(size_t)n * DIMC + d] * NORM_QK;
  }
  __syncthreads();
  for (int n = tid; n < NSEQ; n += 320) {
    float s0 = 0.f, s1 = 0.f, s2 = 0.f, s3 = 0.f;
    const float4* kr = (const float4*)kn_s[n];
#pragma unroll
    for (int c2 = 0; c2 < 16; c2++) {
      const float4 kv = kr[c2];
      s0 += kv.x*kv.x; s1 += kv.y*kv.y; s2 += kv.z*kv.z; s3 += kv.w*kv.w;
    }
    diag_s[n] = 0.5f * ((s0+s1)+(s2+s3));
  }
  const int m = tid;
  const bool act = (m < MF);
  float pr[64];
  {
    const float4* pp = (const float4*)(proj + (size_t)(act ? m : 0) * 64);
#pragma unroll
    for (int c2 = 0; c2 < 16; c2++) {
      const float4 t = pp[c2];
      pr[4*c2] = t.x; pr[4*c2+1] = t.y; pr[4*c2+2] = t.z; pr[4*c2+3] = t.w;
    }
  }
  // pass 1: global max of dd
  float mx = -3.0e38f;
  for (int n = 0; n < NSEQ; n++) {
    const float4* kr = (const float4*)kn_s[n];
    float s0 = 0.f, s1 = 0.f, s2 = 0.f, s3 = 0.f;
#pragma unroll
    for (int c2 = 0; c2 < 16; c2++) {
      const float4 kv = kr[c2];
      s0 += kv.x*pr[4*c2];   s1 += kv.y*pr[4*c2+1];
      s2 += kv.z*pr[4*c2+2]; s3 += kv.w*pr[4*c2+3];
    }
    mx = fmaxf(mx, (s0+s1)+(s2+s3));
  }
  if (!act) mx = -3.0e38f;
#pragma unroll
  for (int off = 32; off; off >>= 1) mx = fmaxf(mx, __shfl_xor(mx, off));
  if ((tid & 63) == 0) red_s[tid >> 6] = mx;
  __syncthreads();
  const float stab = fmaxf(fmaxf(fmaxf(red_s[0], red_s[1]), fmaxf(red_s[2], red_s[3])), red_s[4]);
  // pass 2
  float ctx[64];
#pragma unroll
  for (int i = 0; i < 64; i++) ctx[i] = 0.f;
  float ks = 0.f;
  for (int n = 0; n < NSEQ; n++) {
    const float4* kr = (const float4*)kn_s[n];
    float s0 = 0.f, s1 = 0.f, s2 = 0.f, s3 = 0.f;
#pragma unroll
    for (int c2 = 0; c2 < 16; c2++) {
      const float4 kv = kr[c2];
      s0 += kv.x*pr[4*c2];   s1 += kv.y*pr[4*c2+1];
      s2 += kv.z*pr[4*c2+2]; s3 += kv.w*pr[4*c2+3];
    }
    const float kp = __expf(((s0+s1)+(s2+s3)) - diag_s[n] - stab) + KEPS;
    ks += kp;
    const float4* vr = (const float4*)(Vb + (size_t)n * DIMC);  // broadcast
#pragma unroll
    for (int c2 = 0; c2 < 16; c2++) {
      const float4 vv = vr[c2];
      ctx[4*c2]   += kp * vv.x; ctx[4*c2+1] += kp * vv.y;
      ctx[4*c2+2] += kp * vv.z; ctx[4*c2+3] += kp * vv.w;
    }
  }
  if (act) {
    float* co = ctx_out + ((size_t)bh * MF + m) * 64;
#pragma unroll
    for (int i = 0; i < 64; i++) co[i] = ctx[i];
    ksum_out[(size_t)bh * MF + m] = ks;
  }
}

// ---------------------------------------------------------------------------
// FAVOR+ query-side. One block per (b,h), 512 threads = 8 waves, 8 query rows
// per wave-iteration. qp stored bf16 in LDS; total LDS 159.4 KB (8 waves/CU).
// Output written bf16 (feeds the wo GEMM).
// ---------------------------------------------------------------------------
__global__ __launch_bounds__(512) void favor_out_kernel(
    const float* __restrict__ Qp, const float* __restrict__ proj,
    const float* __restrict__ ctx_in, const float* __restrict__ ksum_in,
    __hip_bfloat16* __restrict__ Ob_out)
{
  __shared__ float proj_s[MF][68];                 // 72,352 B
  __shared__ __hip_bfloat16 ctxT_s[64][272];       // 34,816 B
  __shared__ float qrow_s[8][8][68];               // 17,408 B
  __shared__ __hip_bfloat16 qpb_s[8][8][272];      // 34,816 B  => 159,392 B
  const int tid = threadIdx.x;
  const int bh = blockIdx.x;
  const int b = bh >> 2, h = bh & 3;
  const int w = tid >> 6, lane = tid & 63;

  // zero bf16 pads first (uint-wide), then fill
  for (int idx = tid; idx < 64*136; idx += 512) ((unsigned int*)ctxT_s)[idx] = 0u;
  for (int idx = tid; idx < 8*8*136; idx += 512) ((unsigned int*)qpb_s)[idx] = 0u;
  __syncthreads();
  for (int idx = tid; idx < MF*64; idx += 512)
    proj_s[idx >> 6][idx & 63] = proj[idx];
  const float* cb = ctx_in + (size_t)bh * MF * 64;
  for (int idx = tid; idx < MF*64; idx += 512) {
    const int mm = idx >> 6, d = idx & 63;
    ctxT_s[d][mm] = __float2bfloat16(cb[idx]);
  }
  __syncthreads();

  float ks_r[5];
#pragma unroll
  for (int mb = 0; mb < 5; mb++) {
    const int mm = mb*64 + lane;
    ks_r[mb] = (mm < MF) ? ksum_in[(size_t)bh * MF + mm] : 0.f;
  }

  const float* Qb = Qp + (size_t)b * NSEQ * DIMC + h * 64;
  __hip_bfloat16* Ob = Ob_out + (size_t)b * NSEQ * DIMC + h * 64;

  for (int g = w; g < 38; g += 8) {
    const int n0 = g * 8;
    float diag[8];
#pragma unroll
    for (int j = 0; j < 8; j++) {
      const int n = n0 + j;
      const float qv = (n < NSEQ) ? Qb[(size_t)n * DIMC + lane] * NORM_QK : 0.f;
      qrow_s[w][j][lane] = qv;
      float sq = qv * qv;
#pragma unroll
      for (int off = 32; off; off >>= 1) sq += __shfl_xor(sq, off);
      diag[j] = 0.5f * sq;
    }
    float dd[5][8];
#pragma unroll
    for (int mb = 0; mb < 5; mb++)
#pragma unroll
      for (int j = 0; j < 8; j++) dd[mb][j] = 0.f;
    for (int d0 = 0; d0 < 64; d0 += 4) {
      float4 pv[5];
#pragma unroll
      for (int mb = 0; mb < 5; mb++) {
        const int mm = mb*64 + lane;
        const int mc = mm < MF ? mm : MF - 1;
        pv[mb] = *(const float4*)&proj_s[mc][d0];
      }
#pragma unroll
      for (int j = 0; j < 8; j++) {
        const float4 qv = *(const float4*)&qrow_s[w][j][d0];
#pragma unroll
        for (int mb = 0; mb < 5; mb++)
          dd[mb][j] += qv.x*pv[mb].x + qv.y*pv[mb].y + qv.z*pv[mb].z + qv.w*pv[mb].w;
      }
    }
    float dinv[8];
#pragma unroll
    for (int j = 0; j < 8; j++) {
      float mxx = -3.0e38f;
#pragma unroll
      for (int mb = 0; mb < 5; mb++) {
        const int mm = mb*64 + lane;
        if (mm < MF) mxx = fmaxf(mxx, dd[mb][j]);
      }
#pragma unroll
      for (int off = 32; off; off >>= 1) mxx = fmaxf(mxx, __shfl_xor(mxx, off));
      float dpart = 0.f;
#pragma unroll
      for (int mb = 0; mb < 5; mb++) {
        const int mm = mb*64 + lane;
        float qpv = 0.f;
        if (mm < MF) qpv = __expf(dd[mb][j] - diag[j] - mxx) + KEPS;
        dd[mb][j] = qpv;
        dpart += qpv * ks_r[mb];
      }
#pragma unroll
      for (int off = 32; off; off >>= 1) dpart += __shfl_xor(dpart, off);
      dinv[j] = 1.0f / dpart;
#pragma unroll
      for (int mb = 0; mb < 5; mb++) {
        const int mm = mb*64 + lane;
        if (mm < MF) qpb_s[w][j][mm] = __float2bfloat16(dd[mb][j]);
      }
    }
    // combine: o[j][lane] = dinv[j] * sum_m qp[j][m] * ctxT[lane][m]
    float acc8[8] = {0.f,0.f,0.f,0.f,0.f,0.f,0.f,0.f};
    for (int m0 = 0; m0 < 268; m0 += 4) {
      const ushort4 cu = *(const ushort4*)&ctxT_s[lane][m0];
      const float c0 = bfbits2f(cu.x), c1 = bfbits2f(cu.y);
      const float c2 = bfbits2f(cu.z), c3 = bfbits2f(cu.w);
#pragma unroll
      for (int j = 0; j < 8; j++) {
        const ushort4 qu = *(const ushort4*)&qpb_s[w][j][m0];  // broadcast
        acc8[j] += bfbits2f(qu.x)*c0 + bfbits2f(qu.y)*c1
                 + bfbits2f(qu.z)*c2 + bfbits2f(qu.w)*c3;
      }
    }
#pragma unroll
    for (int j = 0; j < 8; j++) {
      const int n = n0 + j;
      if (n < NSEQ) Ob[(size_t)n * DIMC + lane] = __float2bfloat16(acc8[j] * dinv[j]);
    }
  }
}

// ---------------------------------------------------------------------------
// Mean-pool over N, LayerNorm, 256->128 ReLU, 128->1 sigmoid. Block per batch.
// ---------------------------------------------------------------------------
__global__ __launch_bounds__(256) void head_kernel(
    const float* __restrict__ h, const float* __restrict__ hg,
    const float* __restrict__ hb, const float* __restrict__ wh1,
    const float* __restrict__ bh1, const float* __restrict__ wh2,
    const float* __restrict__ bh2, float* __restrict__ out)
{
  __shared__ float z_s[256];
  __shared__ float hid_s[128];
  __shared__ float red_s[4];
  const int b = blockIdx.x, tid = threadIdx.x;
  const float* hb_ = h + (size_t)b * NSEQ * DIMC;
  float s = 0.f;
  for (int n = 0; n < NSEQ; n++) s += hb_[(size_t)n * DIMC + tid];
  s *= (1.0f / 300.0f);
  float t1 = s;
#pragma unroll
  for (int off = 32; off; off >>= 1) t1 += __shfl_xor(t1, off);
  if ((tid & 63) == 0) red_s[tid >> 6] = t1;
  __syncthreads();
  const float mu = (red_s[0] + red_s[1] + red_s[2] + red_s[3]) * (1.0f/256.0f);
  __syncthreads();
  const float d = s - mu;
  float vv = d * d;
#pragma unroll
  for (int off = 32; off; off >>= 1) vv += __shfl_xor(vv, off);
  if ((tid & 63) == 0) red_s[tid >> 6] = vv;
  __syncthreads();
  const float var = (red_s[0] + red_s[1] + red_s[2] + red_s[3]) * (1.0f/256.0f);
  z_s[tid] = d * rsqrtf(var + 1e-5f) * hg[tid] + hb[tid];
  __syncthreads();
  if (tid < 128) {
    float acc = bh1[tid];
    for (int dd = 0; dd < 256; dd++) acc += z_s[dd] * wh1[dd * 128 + tid];
    hid_s[tid] = fmaxf(acc, 0.f);
  }
  __syncthreads();
  if (tid < 64) {
    float acc = hid_s[tid] * wh2[tid] + hid_s[tid + 64] * wh2[tid + 64];
#pragma unroll
    for (int off = 32; off; off >>= 1) acc += __shfl_xor(acc, off);
    if (tid == 0) {
      const float val = acc + bh2[0];
      out[b] = 1.0f / (1.0f + __expf(-val));
    }
  }
}

// ---------------------------------------------------------------------------
extern "C" void kernel_launch(void* const* d_in, const int* in_sizes, int n_in,
                              void* d_out, int out_size, void* d_ws, size_t ws_size,
                              hipStream_t stream) {
  const float* x    = (const float*)d_in[0];
  const float* w_in = (const float*)d_in[1];
  const float* b_in = (const float*)d_in[2];
  const float* proj = (const float*)d_in[3];
  const float* ln1g = (const float*)d_in[4];
  const float* ln1b = (const float*)d_in[5];
  const float* wq   = (const float*)d_in[6];
  const float* wk   = (const float*)d_in[7];
  const float* wv   = (const float*)d_in[8];
  const float* wo   = (const float*)d_in[9];
  const float* bo   = (const float*)d_in[10];
  const float* ln2g = (const float*)d_in[11];
  const float* ln2b = (const float*)d_in[12];
  const float* w1   = (const float*)d_in[13];
  const float* b1   = (const float*)d_in[14];
  const float* w2   = (const float*)d_in[15];
  const float* b2   = (const float*)d_in[16];
  const float* hg   = (const float*)d_in[17];
  const float* hbp  = (const float*)d_in[18];
  const float* wh1  = (const float*)d_in[19];
  const float* bh1  = (const float*)d_in[20];
  const float* wh2  = (const float*)d_in[21];
  const float* bh2  = (const float*)d_in[22];

  uint8_t* base = (uint8_t*)d_ws;
  float*          h    = (float*)(base);                       // 78,643,200 B
  __hip_bfloat16* yb   = (__hip_bfloat16*)(base + 78643200);   // 39,321,600 B
  float*          q    = (float*)(base + 117964800);           // 78,643,200 B
  float*          k    = (float*)(base + 196608000);           // 78,643,200 B
  float*          v    = (float*)(base + 275251200);           // 78,643,200 B
  __hip_bfloat16* ob   = (__hip_bfloat16*)(base + 353894400);  // 39,321,600 B
  float*          ctx  = (float*)(base + 393216000);           // 69,730,304 B
  float*          ksum = (float*)(base + 462946304);           //  1,089,536 B
  ushort*         wbuf = (ushort*)(base + 464035840);          //  3,801,088 B
  // aliases (lifetimes disjoint):
  __hip_bfloat16* xb = (__hip_bfloat16*)q;   // 196.6 MB over q,k,v
  __hip_bfloat16* tb = (__hip_bfloat16*)q;   // 157.3 MB over q,k

  ushort* w_inT = wbuf;                                  // [256][1280]
  ushort* wT0   = wbuf + 327680;

  // --- weight prep (bf16, transposed to [N][K]) + x cast ------------------
  cast_bf16_kernel<<<(24576000 + 255) / 256, 256, 0, stream>>>(x, xb, 24576000);
  tcast_kernel<<<dim3(8, 40), 256, 0, stream>>>(w_in, (__hip_bfloat16*)w_inT, 1280, 256);
  for (int l = 0; l < 2; l++) {
    ushort* wl = wT0 + (size_t)l * 786432;
    tcast_kernel<<<dim3(8, 8),  256, 0, stream>>>(wq + (size_t)l*65536,  (__hip_bfloat16*)(wl),          256, 256);
    tcast_kernel<<<dim3(8, 8),  256, 0, stream>>>(wk + (size_t)l*65536,  (__hip_bfloat16*)(wl + 65536),  256, 256);
    tcast_kernel<<<dim3(8, 8),  256, 0, stream>>>(wv + (size_t)l*65536,  (__hip_bfloat16*)(wl + 131072), 256, 256);
    tcast_kernel<<<dim3(8, 8),  256, 0, stream>>>(wo + (size_t)l*65536,  (__hip_bfloat16*)(wl + 196608), 256, 256);
    tcast_kernel<<<dim3(32, 8), 256, 0, stream>>>(w1 + (size_t)l*262144, (__hip_bfloat16*)(wl + 262144), 256, 1024);
    tcast_kernel<<<dim3(8, 32), 256, 0, stream>>>(w2 + (size_t)l*262144, (__hip_bfloat16*)(wl + 524288), 1024, 256);
  }

  // --- h = x @ w_in + b_in ------------------------------------------------
  gemm_mfma<0,0><<<dim3(600, 2), 256, 0, stream>>>(
      (const ushort*)xb, w_inT, b_in, nullptr, h, nullptr, 76800, 256, 1280);

  for (int l = 0; l < 2; l++) {
    const float* projL = proj + (size_t)l * MF * 64;
    ushort* wl = wT0 + (size_t)l * 786432;
    ln_kernel<<<19200, 256, 0, stream>>>(h, ln1g + l*256, ln1b + l*256, yb);
    gemm_mfma<3,0><<<dim3(600, 2), 256, 0, stream>>>(
        (const ushort*)yb, wl,          nullptr, nullptr, q, nullptr, 76800, 256, 256);
    gemm_mfma<3,0><<<dim3(600, 2), 256, 0, stream>>>(
        (const ushort*)yb, wl + 65536,  nullptr, nullptr, k, nullptr, 76800, 256, 256);
    gemm_mfma<3,0><<<dim3(600, 2), 256, 0, stream>>>(
        (const ushort*)yb, wl + 131072, nullptr, nullptr, v, nullptr, 76800, 256, 256);
    favor_ctx_kernel<<<1024, 320, 0, stream>>>(k, v, projL, ctx, ksum);
    favor_out_kernel<<<1024, 512, 0, stream>>>(q, projL, ctx, ksum, ob);
    gemm_mfma<1,0><<<dim3(600, 2), 256, 0, stream>>>(
        (const ushort*)ob, wl + 196608, bo + l*256, h, h, nullptr, 76800, 256, 256);
    ln_kernel<<<19200, 256, 0, stream>>>(h, ln2g + l*256, ln2b + l*256, yb);
    gemm_mfma<2,1><<<dim3(600, 8), 256, 0, stream>>>(
        (const ushort*)yb, wl + 262144, b1 + l*1024, nullptr, nullptr, tb, 76800, 1024, 256);
    gemm_mfma<1,0><<<dim3(600, 2), 256, 0, stream>>>(
        (const ushort*)tb, wl + 524288, b2 + l*256, h, h, nullptr, 76800, 256, 1024);
  }
  head_kernel<<<256, 256, 0, stream>>>(h, hg, hbp, wh1, bh1, wh2, bh2, (float*)d_out);
}

// Round 3
// 1974.838 us; speedup vs baseline: 5.4098x; 2.7805x over previous
//
#include <hip/hip_runtime.h>
#include <hip/hip_bf16.h>

// ---------------------------------------------------------------------------
// Performer (FAVOR+) — round 3: MFMA everywhere (GEMMs + both favor kernels).
// B=256, N=300, IN_DIM=1280, DIM=256, DEPTH=2, HEADS=4, DH=64, MF=266, FFH=1024
// ---------------------------------------------------------------------------

#define MF 266
#define NSEQ 300
#define DIMC 256
#define NORM_QK 0.3535533905932738f   // 64^-0.25
#define KEPS 1e-4f

typedef __attribute__((ext_vector_type(8))) short bf16x8;
typedef __attribute__((ext_vector_type(4))) float f32x4;

#define MFMA16(a, b, c) __builtin_amdgcn_mfma_f32_16x16x32_bf16((a), (b), (c), 0, 0, 0)

__device__ __forceinline__ float bfbits2f(ushort u) {
  return __uint_as_float(((unsigned int)u) << 16);
}
__device__ __forceinline__ ushort f2us(float f) {
  __hip_bfloat16 b = __float2bfloat16(f);
  return *(ushort*)&b;
}
__device__ __forceinline__ float sq8(uint4 u) {
  float s = 0.f;
  const unsigned int uu[4] = {u.x, u.y, u.z, u.w};
#pragma unroll
  for (int i = 0; i < 4; i++) {
    const float a = bfbits2f((ushort)(uu[i] & 0xffff));
    const float b = bfbits2f((ushort)(uu[i] >> 16));
    s += a * a + b * b;
  }
  return s;
}

// ---------------------------------------------------------------------------
// bf16 MFMA GEMM: C[M,N] = epi(A[M,K] @ BT[N,K]^T + bias [+R])
// 128x128 tile, BK=32, 4 waves, 4x4 grid of 16x16x32 MFMAs per wave.
// EPI: 0=+bias->f32 ; 1=+bias+residual->f32 ; 2=gelu(+bias)->bf16 ;
//      4=QKV: no bias, out to [tsel][bh][n][64] bf16, q/k scaled by NORM_QK
// ---------------------------------------------------------------------------
template<int EPI, int OUTBF>
__global__ __launch_bounds__(256) void gemm_mfma(
    const ushort* __restrict__ A, const ushort* __restrict__ BT,
    const float* __restrict__ bias, const float* __restrict__ R,
    float* __restrict__ Cf, __hip_bfloat16* __restrict__ Cb,
    ushort* __restrict__ Cq, int M, int N, int K)
{
  __shared__ ushort As[128][32];
  __shared__ ushort Bs[128][32];
  const int tid = threadIdx.x;
  const int row0 = blockIdx.x << 7, col0 = blockIdx.y << 7;
  const int w = tid >> 6, lane = tid & 63;
  const int wm = (w >> 1) << 6, wn = (w & 1) << 6;
  const int r = lane & 15, quad = lane >> 4;
  const int sr = tid >> 2, sc = (tid & 3) << 3;
  f32x4 acc[4][4];
#pragma unroll
  for (int i = 0; i < 4; i++)
#pragma unroll
    for (int j = 0; j < 4; j++) acc[i][j] = (f32x4){0.f, 0.f, 0.f, 0.f};
  const ushort* ap0 = A + (size_t)(row0 + sr) * K + sc;
  const ushort* ap1 = A + (size_t)(row0 + sr + 64) * K + sc;
  const ushort* bp0 = BT + (size_t)(col0 + sr) * K + sc;
  const ushort* bp1 = BT + (size_t)(col0 + sr + 64) * K + sc;
  for (int k0 = 0; k0 < K; k0 += 32) {
    *(uint4*)&As[sr][sc]    = *(const uint4*)(ap0 + k0);
    *(uint4*)&As[sr+64][sc] = *(const uint4*)(ap1 + k0);
    *(uint4*)&Bs[sr][sc]    = *(const uint4*)(bp0 + k0);
    *(uint4*)&Bs[sr+64][sc] = *(const uint4*)(bp1 + k0);
    __syncthreads();
    bf16x8 af[4], bfv[4];
#pragma unroll
    for (int i = 0; i < 4; i++) af[i]  = *(const bf16x8*)&As[wm + i*16 + r][quad << 3];
#pragma unroll
    for (int i = 0; i < 4; i++) bfv[i] = *(const bf16x8*)&Bs[wn + i*16 + r][quad << 3];
#pragma unroll
    for (int mi = 0; mi < 4; mi++)
#pragma unroll
      for (int ni = 0; ni < 4; ni++)
        acc[mi][ni] = MFMA16(af[mi], bfv[ni], acc[mi][ni]);
    __syncthreads();
  }
#pragma unroll
  for (int mi = 0; mi < 4; mi++) {
    const int rowb = row0 + wm + mi*16 + (quad << 2);
#pragma unroll
    for (int ni = 0; ni < 4; ni++) {
      const int col = col0 + wn + ni*16 + r;
      if (EPI == 4) {
        const int tsel = col >> 8, hd = col & 255, hh = hd >> 6, d = hd & 63;
        const float sc_ = (tsel == 2) ? 1.f : NORM_QK;
#pragma unroll
        for (int j = 0; j < 4; j++) {
          const int rowj = rowb + j;
          const int bq = rowj / 300, nq = rowj - bq * 300;
          Cq[(((size_t)tsel * 1024 + (bq << 2) + hh) * 300 + nq) * 64 + d] =
              f2us(acc[mi][ni][j] * sc_);
        }
      } else {
        const float bv = bias[col];
#pragma unroll
        for (int j = 0; j < 4; j++) {
          const size_t off = (size_t)(rowb + j) * N + col;
          float vv = acc[mi][ni][j] + bv;
          if (EPI == 1) vv += R[off];
          if (EPI == 2) {
            const float xx = vv;
            vv = 0.5f * xx * (1.0f + tanhf(0.7978845608028654f * (xx + 0.044715f * xx * xx * xx)));
          }
          if (OUTBF) Cb[off] = __float2bfloat16(vv);
          else       Cf[off] = vv;
        }
      }
    }
  }
}

// ---------------------------------------------------------------------------
__global__ __launch_bounds__(256) void cast_bf16_kernel(
    const float* __restrict__ in, ushort* __restrict__ out, int n4)
{
  const int i = blockIdx.x * 256 + threadIdx.x;
  if (i >= n4) return;
  const float4 v = ((const float4*)in)[i];
  ushort4 rr;
  rr.x = f2us(v.x); rr.y = f2us(v.y); rr.z = f2us(v.z); rr.w = f2us(v.w);
  ((ushort4*)out)[i] = rr;
}

// fp32 [R][C] -> bf16 [C][R] transpose-cast, 32x32 tiles.
__global__ __launch_bounds__(256) void tcast_kernel(
    const float* __restrict__ in, __hip_bfloat16* __restrict__ out, int R, int C)
{
  __shared__ float t[32][33];
  const int c0 = blockIdx.x * 32, r0 = blockIdx.y * 32;
  const int tx = threadIdx.x & 31, ty = threadIdx.x >> 5;
#pragma unroll
  for (int i = 0; i < 32; i += 8)
    t[ty + i][tx] = in[(size_t)(r0 + ty + i) * C + c0 + tx];
  __syncthreads();
#pragma unroll
  for (int i = 0; i < 32; i += 8)
    out[(size_t)(c0 + ty + i) * R + r0 + tx] = __float2bfloat16(t[tx][ty + i]);
}

// LayerNorm over last dim (256), bf16 out. One wave per row, 4 rows/block.
__global__ __launch_bounds__(256) void ln_kernel(
    const float* __restrict__ x, const float* __restrict__ g,
    const float* __restrict__ b, __hip_bfloat16* __restrict__ y)
{
  const int wid = threadIdx.x >> 6, lane = threadIdx.x & 63;
  const int row = blockIdx.x * 4 + wid;
  const float* xr = x + (size_t)row * DIMC;
  float v[4];
  float s = 0.f;
#pragma unroll
  for (int i = 0; i < 4; i++) { v[i] = xr[lane + 64*i]; s += v[i]; }
#pragma unroll
  for (int off = 32; off; off >>= 1) s += __shfl_xor(s, off);
  const float mu = s * (1.0f/256.0f);
  float var = 0.f;
#pragma unroll
  for (int i = 0; i < 4; i++) { const float d = v[i] - mu; var += d*d; }
#pragma unroll
  for (int off = 32; off; off >>= 1) var += __shfl_xor(var, off);
  const float rstd = rsqrtf(var * (1.0f/256.0f) + 1e-5f);
  __hip_bfloat16* yr = y + (size_t)row * DIMC;
#pragma unroll
  for (int i = 0; i < 4; i++) {
    const int c = lane + 64*i;
    yr[c] = __float2bfloat16((v[i] - mu) * rstd * g[c] + b[c]);
  }
}

// ---------------------------------------------------------------------------
// FAVOR+ key-side, MFMA. One block per (b,h), 512 threads = 8 waves.
// ddT[m][n] = proj @ kn^T (tiles via mfma), stab = max; kp = exp(..)+eps in
// 10 chunks of 32 n; ctx[m][d] += kpT_chunk @ vT_chunk; ksum scalar.
// LDS 150,304 B -> 1 block/CU.
// ---------------------------------------------------------------------------
__global__ __launch_bounds__(512) void favor_ctx_kernel(
    const ushort* __restrict__ kn_all, const ushort* __restrict__ v_all,
    const ushort* __restrict__ projb,
    ushort* __restrict__ ctx_g, float* __restrict__ ksum_g)
{
  __shared__ ushort kn_s[320][72];    // rows n>=300 zero  (stride 72: bank spread)
  __shared__ ushort vT_s[64][328];    // cols n>=300 zero
  __shared__ ushort proj_s[272][72];  // rows m>=266 zero
  __shared__ ushort kpT_s[272][40];   // per-chunk kp^T [m][n-local 32]
  __shared__ float diag_s[320];
  __shared__ float red_s[8];
  const int tid = threadIdx.x, w = tid >> 6, lane = tid & 63;
  const int bh = blockIdx.x;
  const int r = lane & 15, quad = lane >> 4;
  const int rl = lane >> 3, c8 = lane & 7;   // 8 lanes per 64-elem row

  // --- staging ---
  const ushort* knb = kn_all + (size_t)bh * 19200;
  for (int row = w*8 + rl; row < 320; row += 64) {
    uint4 u = {0u,0u,0u,0u};
    if (row < 300) u = *(const uint4*)(knb + row*64 + c8*8);
    *(uint4*)&kn_s[row][c8*8] = u;
    float s = sq8(u);
    s += __shfl_xor(s, 1); s += __shfl_xor(s, 2); s += __shfl_xor(s, 4);
    if (c8 == 0) diag_s[row] = 0.5f * s;
  }
  const ushort* vb = v_all + (size_t)bh * 19200;
  for (int row = w*8 + rl; row < 328; row += 64) {
    uint4 u = {0u,0u,0u,0u};
    if (row < 300) u = *(const uint4*)(vb + row*64 + c8*8);
    const unsigned int uu[4] = {u.x, u.y, u.z, u.w};
#pragma unroll
    for (int p = 0; p < 4; p++) {
      vT_s[c8*8 + 2*p    ][row] = (ushort)(uu[p] & 0xffff);
      vT_s[c8*8 + 2*p + 1][row] = (ushort)(uu[p] >> 16);
    }
  }
  for (int row = w*8 + rl; row < 272; row += 64) {
    uint4 u = {0u,0u,0u,0u};
    if (row < 266) u = *(const uint4*)(projb + row*64 + c8*8);
    *(uint4*)&proj_s[row][c8*8] = u;
  }
  __syncthreads();

  // --- pass 1: stab = max dd over valid (m,n) ---
  float mx = -3.0e38f;
  for (int t = w; t < 340; t += 8) {
    const int tm = t / 20, tn = t % 20;
    if (tn == 19) continue;                   // n >= 304: all invalid
    const bf16x8 a0 = *(const bf16x8*)&proj_s[tm*16 + r][quad*8];
    const bf16x8 a1 = *(const bf16x8*)&proj_s[tm*16 + r][32 + quad*8];
    const bf16x8 b0 = *(const bf16x8*)&kn_s[tn*16 + r][quad*8];
    const bf16x8 b1 = *(const bf16x8*)&kn_s[tn*16 + r][32 + quad*8];
    f32x4 acc = (f32x4){0.f,0.f,0.f,0.f};
    acc = MFMA16(a0, b0, acc);
    acc = MFMA16(a1, b1, acc);
    const int n = tn*16 + r;                  // C col
    if (n < 300) {
#pragma unroll
      for (int j = 0; j < 4; j++) {
        const int m = tm*16 + quad*4 + j;     // C row
        if (m < 266) mx = fmaxf(mx, acc[j]);
      }
    }
  }
#pragma unroll
  for (int off = 32; off; off >>= 1) mx = fmaxf(mx, __shfl_xor(mx, off));
  if (lane == 0) red_s[w] = mx;
  __syncthreads();
  float stab = red_s[0];
#pragma unroll
  for (int i = 1; i < 8; i++) stab = fmaxf(stab, red_s[i]);

  // --- pass 2: chunks of 32 n ---
  f32x4 cacc[9];
#pragma unroll
  for (int i = 0; i < 9; i++) cacc[i] = (f32x4){0.f,0.f,0.f,0.f};
  float ksum_acc = 0.f;

  for (int c = 0; c < 10; c++) {
    for (int t = w; t < 34; t += 8) {
      const int tm = t >> 1, tnl = t & 1, tn = c*2 + tnl;
      const bf16x8 a0 = *(const bf16x8*)&proj_s[tm*16 + r][quad*8];
      const bf16x8 a1 = *(const bf16x8*)&proj_s[tm*16 + r][32 + quad*8];
      const bf16x8 b0 = *(const bf16x8*)&kn_s[tn*16 + r][quad*8];
      const bf16x8 b1 = *(const bf16x8*)&kn_s[tn*16 + r][32 + quad*8];
      f32x4 acc = (f32x4){0.f,0.f,0.f,0.f};
      acc = MFMA16(a0, b0, acc);
      acc = MFMA16(a1, b1, acc);
      const int n = tn*16 + r;
#pragma unroll
      for (int j = 0; j < 4; j++) {
        const int m = tm*16 + quad*4 + j;
        float kp = 0.f;
        if (n < 300 && m < 266) kp = __expf(acc[j] - diag_s[n] - stab) + KEPS;
        kpT_s[m][tnl*16 + r] = f2us(kp);
      }
    }
    __syncthreads();
    if (tid < 272) {
#pragma unroll
      for (int kk = 0; kk < 4; kk++) {
        const uint4 u = *(const uint4*)&kpT_s[tid][kk*8];
        const unsigned int uu[4] = {u.x, u.y, u.z, u.w};
#pragma unroll
        for (int p = 0; p < 4; p++)
          ksum_acc += bfbits2f((ushort)(uu[p] & 0xffff)) + bfbits2f((ushort)(uu[p] >> 16));
      }
    }
#pragma unroll
    for (int ii = 0; ii < 9; ii++) {
      const int t2 = w + ii*8;
      if (t2 < 68) {
        const int tm = t2 >> 2, td = t2 & 3;
        const bf16x8 aa = *(const bf16x8*)&kpT_s[tm*16 + r][quad*8];
        const bf16x8 bb = *(const bf16x8*)&vT_s[td*16 + r][c*32 + quad*8];
        cacc[ii] = MFMA16(aa, bb, cacc[ii]);
      }
    }
    __syncthreads();
  }

  // --- store ctx (bf16 [bh][266][64]) + ksum ---
#pragma unroll
  for (int ii = 0; ii < 9; ii++) {
    const int t2 = w + ii*8;
    if (t2 < 68) {
      const int tm = t2 >> 2, td = t2 & 3;
#pragma unroll
      for (int j = 0; j < 4; j++) {
        const int m = tm*16 + quad*4 + j;
        if (m < 266)
          ctx_g[((size_t)bh*266 + m)*64 + td*16 + r] = f2us(cacc[ii][j]);
      }
    }
  }
  if (tid < 266) ksum_g[(size_t)bh*266 + tid] = ksum_acc;
}

// ---------------------------------------------------------------------------
// FAVOR+ query-side, MFMA. One block per (b,h), 512 threads = 8 waves.
// Wave owns n-tiles {w, w+8, w+16} < 19. dd = qn @ proj^T per tile (C-layout),
// rowmax + denom via 16-lane shuffles, qp -> per-wave LDS (no barrier),
// o = qp @ ctxT via MFMA (K=288 in 3 groups of 96), scaled by dinv.
// LDS 152,128 B.
// ---------------------------------------------------------------------------
__global__ __launch_bounds__(512) void favor_out_kernel(
    const ushort* __restrict__ qn_all, const ushort* __restrict__ projb,
    const ushort* __restrict__ ctxb, const float* __restrict__ ksum_g,
    ushort* __restrict__ Ob)
{
  __shared__ ushort qn_s[320][72];
  __shared__ ushort proj_s[272][72];
  __shared__ ushort ctxT_s[64][296];   // [d][m], cols m>=266 zero
  __shared__ ushort qp_s[8][16][104];  // per-wave A-operand buffer
  __shared__ float ksum_s[272];
  __shared__ float diag_s[320];
  const int tid = threadIdx.x, w = tid >> 6, lane = tid & 63;
  const int bh = blockIdx.x;
  const int b = bh >> 2, h = bh & 3;
  const int r = lane & 15, quad = lane >> 4;
  const int rl = lane >> 3, c8 = lane & 7;

  // --- staging ---
  const ushort* qb = qn_all + (size_t)bh * 19200;
  for (int row = w*8 + rl; row < 320; row += 64) {
    uint4 u = {0u,0u,0u,0u};
    if (row < 300) u = *(const uint4*)(qb + row*64 + c8*8);
    *(uint4*)&qn_s[row][c8*8] = u;
    float s = sq8(u);
    s += __shfl_xor(s, 1); s += __shfl_xor(s, 2); s += __shfl_xor(s, 4);
    if (c8 == 0) diag_s[row] = 0.5f * s;
  }
  for (int row = w*8 + rl; row < 272; row += 64) {
    uint4 u = {0u,0u,0u,0u};
    if (row < 266) u = *(const uint4*)(projb + row*64 + c8*8);
    *(uint4*)&proj_s[row][c8*8] = u;
  }
  const ushort* cb = ctxb + (size_t)bh * 266 * 64;
  for (int m = w*8 + rl; m < 296; m += 64) {
    uint4 u = {0u,0u,0u,0u};
    if (m < 266) u = *(const uint4*)(cb + m*64 + c8*8);
    const unsigned int uu[4] = {u.x, u.y, u.z, u.w};
#pragma unroll
    for (int p = 0; p < 4; p++) {
      ctxT_s[c8*8 + 2*p    ][m] = (ushort)(uu[p] & 0xffff);
      ctxT_s[c8*8 + 2*p + 1][m] = (ushort)(uu[p] >> 16);
    }
  }
  if (tid < 272) ksum_s[tid] = (tid < 266) ? ksum_g[(size_t)bh*266 + tid] : 0.f;
  __syncthreads();

  // --- per owned n-tile ---
  for (int t = w; t < 19; t += 8) {
    const bf16x8 a0 = *(const bf16x8*)&qn_s[t*16 + r][quad*8];
    const bf16x8 a1 = *(const bf16x8*)&qn_s[t*16 + r][32 + quad*8];
    f32x4 dd[17];
#pragma unroll
    for (int tm = 0; tm < 17; tm++) {
      const bf16x8 b0 = *(const bf16x8*)&proj_s[tm*16 + r][quad*8];
      const bf16x8 b1 = *(const bf16x8*)&proj_s[tm*16 + r][32 + quad*8];
      f32x4 acc = (f32x4){0.f,0.f,0.f,0.f};
      acc = MFMA16(a0, b0, acc);
      acc = MFMA16(a1, b1, acc);
      dd[tm] = acc;
    }
    // rowmax over valid m (col m = tm*16 + r)
    float mxj[4] = {-3.0e38f, -3.0e38f, -3.0e38f, -3.0e38f};
#pragma unroll
    for (int tm = 0; tm < 17; tm++) {
      if (tm*16 + r < 266) {
#pragma unroll
        for (int j = 0; j < 4; j++) mxj[j] = fmaxf(mxj[j], dd[tm][j]);
      }
    }
#pragma unroll
    for (int off = 1; off < 16; off <<= 1)
#pragma unroll
      for (int j = 0; j < 4; j++) mxj[j] = fmaxf(mxj[j], __shfl_xor(mxj[j], off));
    float dg[4];
#pragma unroll
    for (int j = 0; j < 4; j++) dg[j] = diag_s[t*16 + quad*4 + j];
    // qp + denom
    float den[4] = {0.f, 0.f, 0.f, 0.f};
#pragma unroll
    for (int tm = 0; tm < 17; tm++) {
      const float ks = ksum_s[tm*16 + r];
      const bool mval = (tm*16 + r < 266);
#pragma unroll
      for (int j = 0; j < 4; j++) {
        const int n = t*16 + quad*4 + j;
        float qp = 0.f;
        if (mval && n < 300) qp = __expf(dd[tm][j] - dg[j] - mxj[j]) + KEPS;
        dd[tm][j] = qp;
        den[j] += qp * ks;
      }
    }
#pragma unroll
    for (int off = 1; off < 16; off <<= 1)
#pragma unroll
      for (int j = 0; j < 4; j++) den[j] += __shfl_xor(den[j], off);
    float dinv[4];
#pragma unroll
    for (int j = 0; j < 4; j++) dinv[j] = 1.0f / den[j];

    // o = qp @ ctxT, K = 288 in 3 groups of 96 (tm 17 virtual = zeros)
    f32x4 oacc[4];
#pragma unroll
    for (int td = 0; td < 4; td++) oacc[td] = (f32x4){0.f,0.f,0.f,0.f};
#pragma unroll
    for (int g = 0; g < 3; g++) {
#pragma unroll
      for (int tt = 0; tt < 6; tt++) {
        const int tm = g*6 + tt;
#pragma unroll
        for (int j = 0; j < 4; j++) {
          const ushort us = (tm <= 16) ? f2us(dd[tm][j]) : (ushort)0;
          qp_s[w][quad*4 + j][tm*16 + r - g*96] = us;
        }
      }
#pragma unroll
      for (int s = 0; s < 3; s++) {
        const bf16x8 aa = *(const bf16x8*)&qp_s[w][r][s*32 + quad*8];
#pragma unroll
        for (int td = 0; td < 4; td++) {
          const bf16x8 bb = *(const bf16x8*)&ctxT_s[td*16 + r][g*96 + s*32 + quad*8];
          oacc[td] = MFMA16(aa, bb, oacc[td]);
        }
      }
    }
    // store o (bf16 [b*300+n][256])
#pragma unroll
    for (int td = 0; td < 4; td++) {
#pragma unroll
      for (int j = 0; j < 4; j++) {
        const int n = t*16 + quad*4 + j;
        if (n < 300)
          Ob[((size_t)b*300 + n)*256 + h*64 + td*16 + r] = f2us(oacc[td][j] * dinv[j]);
      }
    }
  }
}

// ---------------------------------------------------------------------------
// Mean-pool over N, LayerNorm, 256->128 ReLU, 128->1 sigmoid. Block per batch.
// ---------------------------------------------------------------------------
__global__ __launch_bounds__(256) void head_kernel(
    const float* __restrict__ h, const float* __restrict__ hg,
    const float* __restrict__ hb, const float* __restrict__ wh1,
    const float* __restrict__ bh1, const float* __restrict__ wh2,
    const float* __restrict__ bh2, float* __restrict__ out)
{
  __shared__ float z_s[256];
  __shared__ float hid_s[128];
  __shared__ float red_s[4];
  const int b = blockIdx.x, tid = threadIdx.x;
  const float* hb_ = h + (size_t)b * NSEQ * DIMC;
  float s = 0.f;
  for (int n = 0; n < NSEQ; n++) s += hb_[(size_t)n * DIMC + tid];
  s *= (1.0f / 300.0f);
  float t1 = s;
#pragma unroll
  for (int off = 32; off; off >>= 1) t1 += __shfl_xor(t1, off);
  if ((tid & 63) == 0) red_s[tid >> 6] = t1;
  __syncthreads();
  const float mu = (red_s[0] + red_s[1] + red_s[2] + red_s[3]) * (1.0f/256.0f);
  __syncthreads();
  const float d = s - mu;
  float vv = d * d;
#pragma unroll
  for (int off = 32; off; off >>= 1) vv += __shfl_xor(vv, off);
  if ((tid & 63) == 0) red_s[tid >> 6] = vv;
  __syncthreads();
  const float var = (red_s[0] + red_s[1] + red_s[2] + red_s[3]) * (1.0f/256.0f);
  z_s[tid] = d * rsqrtf(var + 1e-5f) * hg[tid] + hb[tid];
  __syncthreads();
  if (tid < 128) {
    float acc = bh1[tid];
    for (int dd = 0; dd < 256; dd++) acc += z_s[dd] * wh1[dd * 128 + tid];
    hid_s[tid] = fmaxf(acc, 0.f);
  }
  __syncthreads();
  if (tid < 64) {
    float acc = hid_s[tid] * wh2[tid] + hid_s[tid + 64] * wh2[tid + 64];
#pragma unroll
    for (int off = 32; off; off >>= 1) acc += __shfl_xor(acc, off);
    if (tid == 0) {
      const float val = acc + bh2[0];
      out[b] = 1.0f / (1.0f + __expf(-val));
    }
  }
}

// ---------------------------------------------------------------------------
extern "C" void kernel_launch(void* const* d_in, const int* in_sizes, int n_in,
                              void* d_out, int out_size, void* d_ws, size_t ws_size,
                              hipStream_t stream) {
  const float* x    = (const float*)d_in[0];
  const float* w_in = (const float*)d_in[1];
  const float* b_in = (const float*)d_in[2];
  const float* proj = (const float*)d_in[3];
  const float* ln1g = (const float*)d_in[4];
  const float* ln1b = (const float*)d_in[5];
  const float* wq   = (const float*)d_in[6];
  const float* wk   = (const float*)d_in[7];
  const float* wv   = (const float*)d_in[8];
  const float* wo   = (const float*)d_in[9];
  const float* bo   = (const float*)d_in[10];
  const float* ln2g = (const float*)d_in[11];
  const float* ln2b = (const float*)d_in[12];
  const float* w1   = (const float*)d_in[13];
  const float* b1   = (const float*)d_in[14];
  const float* w2   = (const float*)d_in[15];
  const float* b2   = (const float*)d_in[16];
  const float* hg   = (const float*)d_in[17];
  const float* hbp  = (const float*)d_in[18];
  const float* wh1  = (const float*)d_in[19];
  const float* bh1  = (const float*)d_in[20];
  const float* wh2  = (const float*)d_in[21];
  const float* bh2  = (const float*)d_in[22];

  uint8_t* base = (uint8_t*)d_ws;
  float*  h     = (float*)(base);                        // 78,643,200 B
  ushort* yb    = (ushort*)(base + 78643200);            // 39,321,600 B (alias xb start)
  ushort* qkv   = (ushort*)(base + 117964800);           // 117,964,800 B
  ushort* ob    = (ushort*)(base + 235929600);           // 39,321,600 B
  ushort* ctxb  = (ushort*)(base + 275251200);           // 34,865,152 B
  float*  ksum  = (float*)(base + 310116352);            //  1,089,536 B
  ushort* wbuf  = (ushort*)(base + 311205888);           //  3,801,088 B
  ushort* projb = (ushort*)(base + 315006976);           //     68,096 B
  // aliases (disjoint lifetimes):
  ushort* xb = yb;                       // [76800][1280] bf16 over yb+qkv+ob
  ushort* tb = qkv;                      // FFN hidden [76800][1024] over qkv+ob
  ushort* qb = qkv;
  ushort* kb = qkv + 19660800;
  ushort* vb = qkv + 39321600;

  ushort* w_inT = wbuf;                  // [256][1280]
  ushort* wT0   = wbuf + 327680;

  // --- prep: casts + weight transposes ---
  cast_bf16_kernel<<<96000, 256, 0, stream>>>(x, xb, 24576000);
  cast_bf16_kernel<<<34, 256, 0, stream>>>(proj, projb, 8512);
  tcast_kernel<<<dim3(8, 40), 256, 0, stream>>>(w_in, (__hip_bfloat16*)w_inT, 1280, 256);
  for (int l = 0; l < 2; l++) {
    ushort* wl = wT0 + (size_t)l * 786432;
    tcast_kernel<<<dim3(8, 8),  256, 0, stream>>>(wq + (size_t)l*65536,  (__hip_bfloat16*)(wl),          256, 256);
    tcast_kernel<<<dim3(8, 8),  256, 0, stream>>>(wk + (size_t)l*65536,  (__hip_bfloat16*)(wl + 65536),  256, 256);
    tcast_kernel<<<dim3(8, 8),  256, 0, stream>>>(wv + (size_t)l*65536,  (__hip_bfloat16*)(wl + 131072), 256, 256);
    tcast_kernel<<<dim3(8, 8),  256, 0, stream>>>(wo + (size_t)l*65536,  (__hip_bfloat16*)(wl + 196608), 256, 256);
    tcast_kernel<<<dim3(32, 8), 256, 0, stream>>>(w1 + (size_t)l*262144, (__hip_bfloat16*)(wl + 262144), 256, 1024);
    tcast_kernel<<<dim3(8, 32), 256, 0, stream>>>(w2 + (size_t)l*262144, (__hip_bfloat16*)(wl + 524288), 1024, 256);
  }

  // --- h = x @ w_in + b_in ---
  gemm_mfma<0,0><<<dim3(600, 2), 256, 0, stream>>>(
      xb, w_inT, b_in, nullptr, h, nullptr, nullptr, 76800, 256, 1280);

  for (int l = 0; l < 2; l++) {
    ushort* wl = wT0 + (size_t)l * 786432;
    ushort* projL = projb + (size_t)l * 17024;
    ln_kernel<<<19200, 256, 0, stream>>>(h, ln1g + l*256, ln1b + l*256, (__hip_bfloat16*)yb);
    // fused QKV: N=768, writes prescaled bf16 [tsel][bh][n][64]
    gemm_mfma<4,0><<<dim3(600, 6), 256, 0, stream>>>(
        yb, wl, nullptr, nullptr, nullptr, nullptr, qkv, 76800, 768, 256);
    favor_ctx_kernel<<<1024, 512, 0, stream>>>(kb, vb, projL, ctxb, ksum);
    favor_out_kernel<<<1024, 512, 0, stream>>>(qb, projL, ctxb, ksum, ob);
    gemm_mfma<1,0><<<dim3(600, 2), 256, 0, stream>>>(
        ob, wl + 196608, bo + l*256, h, h, nullptr, nullptr, 76800, 256, 256);
    ln_kernel<<<19200, 256, 0, stream>>>(h, ln2g + l*256, ln2b + l*256, (__hip_bfloat16*)yb);
    gemm_mfma<2,1><<<dim3(600, 8), 256, 0, stream>>>(
        yb, wl + 262144, b1 + l*1024, nullptr, nullptr, (__hip_bfloat16*)tb, nullptr, 76800, 1024, 256);
    gemm_mfma<1,0><<<dim3(600, 2), 256, 0, stream>>>(
        tb, wl + 524288, b2 + l*256, h, h, nullptr, nullptr, 76800, 256, 1024);
  }
  head_kernel<<<256, 256, 0, stream>>>(h, hg, hbp, wh1, bh1, wh2, bh2, (float*)d_out);
}

// Round 4
// 1792.969 us; speedup vs baseline: 5.9585x; 1.1014x over previous
//
#include <hip/hip_runtime.h>
#include <hip/hip_bf16.h>

// ---------------------------------------------------------------------------
// Performer (FAVOR+) — round 4: global_load_lds GEMMs, fused online favor,
// fewer launches. B=256,N=300,IN=1280,DIM=256,L=2,H=4,DH=64,MF=266,FFH=1024
// ---------------------------------------------------------------------------

#define MF 266
#define NSEQ 300
#define DIMC 256
#define NORM_QK 0.3535533905932738f   // 64^-0.25
#define KEPS 1e-4f

typedef __attribute__((ext_vector_type(8))) short bf16x8;
typedef __attribute__((ext_vector_type(4))) float f32x4;

#define MFMA16(a, b, c) __builtin_amdgcn_mfma_f32_16x16x32_bf16((a), (b), (c), 0, 0, 0)

__device__ __forceinline__ float bfbits2f(ushort u) {
  return __uint_as_float(((unsigned int)u) << 16);
}
__device__ __forceinline__ ushort f2us(float f) {
  __hip_bfloat16 b = __float2bfloat16(f);
  return *(ushort*)&b;
}
__device__ __forceinline__ float sq8(uint4 u) {
  float s = 0.f;
  const unsigned int uu[4] = {u.x, u.y, u.z, u.w};
#pragma unroll
  for (int i = 0; i < 4; i++) {
    const float a = bfbits2f((ushort)(uu[i] & 0xffff));
    const float b = bfbits2f((ushort)(uu[i] >> 16));
    s += a * a + b * b;
  }
  return s;
}
// async global->LDS, 16B per lane; LDS dst must be waveBase + lane*16 (it is:
// all staging layouts below are byte-linear in tid).
__device__ __forceinline__ void gld16(const void* g, void* l) {
  __builtin_amdgcn_global_load_lds(
      (const __attribute__((address_space(1))) unsigned int*)g,
      (__attribute__((address_space(3))) unsigned int*)l, 16, 0, 0);
}
__device__ __forceinline__ float fast_gelu(float x) {
  const float t = 0.7978845608028654f * (x + 0.044715f * x * x * x);
  const float e = __expf(2.0f * fabsf(t));          // inf-safe: th -> 1
  float th = 1.0f - 2.0f / (e + 1.0f);
  th = (t < 0.0f) ? -th : th;
  return 0.5f * x * (1.0f + th);
}

// ---------------------------------------------------------------------------
// bf16 MFMA GEMM: C[M,N] = epi(A[M,K] @ BT[N,K]^T + bias [+R])
// 128x128 tile, BK=32, 4 waves, 4x4 grid of 16x16x32 MFMAs per wave.
// Staging via global_load_lds (16B/lane); AF32=1: A is fp32, staged via VGPR.
// EPI: 0=+bias->f32 ; 1=+bias+residual->f32 ; 2=gelu(+bias)->bf16 ;
//      4=QKV: no bias, out bf16 [tsel][bh][n][64], q/k prescaled by NORM_QK
// ---------------------------------------------------------------------------
template<int EPI, int OUTBF, int AF32>
__global__ __launch_bounds__(256) void gemm_mfma(
    const ushort* __restrict__ A, const float* __restrict__ Af,
    const ushort* __restrict__ BT,
    const float* __restrict__ bias, const float* __restrict__ R,
    float* __restrict__ Cf, __hip_bfloat16* __restrict__ Cb,
    ushort* __restrict__ Cq, int M, int N, int K)
{
  __shared__ ushort As[128][32];   // byte offset of [tid>>2][(tid&3)*8] == tid*16
  __shared__ ushort Bs[128][32];
  const int tid = threadIdx.x;
  const int row0 = blockIdx.x << 7, col0 = blockIdx.y << 7;
  const int w = tid >> 6, lane = tid & 63;
  const int wm = (w >> 1) << 6, wn = (w & 1) << 6;
  const int r = lane & 15, quad = lane >> 4;
  const int sr = tid >> 2, sc = (tid & 3) << 3;
  f32x4 acc[4][4];
#pragma unroll
  for (int i = 0; i < 4; i++)
#pragma unroll
    for (int j = 0; j < 4; j++) acc[i][j] = (f32x4){0.f, 0.f, 0.f, 0.f};
  const ushort* ap0 = A + (size_t)(row0 + sr) * K + sc;
  const ushort* ap1 = A + (size_t)(row0 + sr + 64) * K + sc;
  const float*  af0 = Af + (size_t)(row0 + sr) * K + sc;
  const float*  af1 = Af + (size_t)(row0 + sr + 64) * K + sc;
  const ushort* bp0 = BT + (size_t)(col0 + sr) * K + sc;
  const ushort* bp1 = BT + (size_t)(col0 + sr + 64) * K + sc;
  for (int k0 = 0; k0 < K; k0 += 32) {
    if (AF32) {
      const float4 u0 = *(const float4*)(af0 + k0);
      const float4 u1 = *(const float4*)(af0 + k0 + 4);
      const float4 u2 = *(const float4*)(af1 + k0);
      const float4 u3 = *(const float4*)(af1 + k0 + 4);
      ushort4 p0, p1, p2, p3;
      p0.x=f2us(u0.x); p0.y=f2us(u0.y); p0.z=f2us(u0.z); p0.w=f2us(u0.w);
      p1.x=f2us(u1.x); p1.y=f2us(u1.y); p1.z=f2us(u1.z); p1.w=f2us(u1.w);
      p2.x=f2us(u2.x); p2.y=f2us(u2.y); p2.z=f2us(u2.z); p2.w=f2us(u2.w);
      p3.x=f2us(u3.x); p3.y=f2us(u3.y); p3.z=f2us(u3.z); p3.w=f2us(u3.w);
      *(ushort4*)&As[sr][sc]      = p0;
      *(ushort4*)&As[sr][sc+4]    = p1;
      *(ushort4*)&As[sr+64][sc]   = p2;
      *(ushort4*)&As[sr+64][sc+4] = p3;
    } else {
      gld16(ap0 + k0, &As[sr][sc]);
      gld16(ap1 + k0, &As[sr + 64][sc]);
    }
    gld16(bp0 + k0, &Bs[sr][sc]);
    gld16(bp1 + k0, &Bs[sr + 64][sc]);
    __syncthreads();
    bf16x8 af[4], bfv[4];
#pragma unroll
    for (int i = 0; i < 4; i++) af[i]  = *(const bf16x8*)&As[wm + i*16 + r][quad << 3];
#pragma unroll
    for (int i = 0; i < 4; i++) bfv[i] = *(const bf16x8*)&Bs[wn + i*16 + r][quad << 3];
#pragma unroll
    for (int mi = 0; mi < 4; mi++)
#pragma unroll
      for (int ni = 0; ni < 4; ni++)
        acc[mi][ni] = MFMA16(af[mi], bfv[ni], acc[mi][ni]);
    __syncthreads();
  }
  // epilogue: C/D layout col=lane&15, row=quad*4+reg
#pragma unroll
  for (int mi = 0; mi < 4; mi++) {
    const int rowb = row0 + wm + mi*16 + (quad << 2);
#pragma unroll
    for (int ni = 0; ni < 4; ni++) {
      const int col = col0 + wn + ni*16 + r;
      if (EPI == 4) {
        const int tsel = col >> 8, hd = col & 255, hh = hd >> 6, d = hd & 63;
        const float sc_ = (tsel == 2) ? 1.f : NORM_QK;
#pragma unroll
        for (int j = 0; j < 4; j++) {
          const int rowj = rowb + j;
          const int bq = rowj / 300, nq = rowj - bq * 300;
          Cq[(((size_t)tsel * 1024 + (bq << 2) + hh) * 300 + nq) * 64 + d] =
              f2us(acc[mi][ni][j] * sc_);
        }
      } else {
        const float bv = bias[col];
#pragma unroll
        for (int j = 0; j < 4; j++) {
          const size_t off = (size_t)(rowb + j) * N + col;
          float vv = acc[mi][ni][j] + bv;
          if (EPI == 1) vv += R[off];
          if (EPI == 2) vv = fast_gelu(vv);
          if (OUTBF) Cb[off] = __float2bfloat16(vv);
          else       Cf[off] = vv;
        }
      }
    }
  }
}

// ---------------------------------------------------------------------------
__global__ __launch_bounds__(256) void cast_bf16_kernel(
    const float* __restrict__ in, ushort* __restrict__ out, int n4)
{
  const int i = blockIdx.x * 256 + threadIdx.x;
  if (i >= n4) return;
  const float4 v = ((const float4*)in)[i];
  ushort4 rr;
  rr.x = f2us(v.x); rr.y = f2us(v.y); rr.z = f2us(v.z); rr.w = f2us(v.w);
  ((ushort4*)out)[i] = rr;
}

// All 13 weight transpose-casts in one launch. [R][C] fp32 -> [C][R] bf16.
struct TSeg { const float* src; ushort* dst; int R; int C; int base; };
struct TTab { TSeg s[13]; };
__global__ __launch_bounds__(256) void tcast_all(TTab tab) {
  __shared__ float t[32][33];
  const int bid = blockIdx.x;
  int si = 0;
#pragma unroll
  for (int i = 1; i < 13; i++) if (bid >= tab.s[i].base) si = i;
  const float* src = tab.s[si].src;
  ushort* dst = tab.s[si].dst;
  const int R = tab.s[si].R, C = tab.s[si].C;
  const int local = bid - tab.s[si].base;
  const int cw = C >> 5;
  const int c0 = (local % cw) << 5, r0 = (local / cw) << 5;
  const int tx = threadIdx.x & 31, ty = threadIdx.x >> 5;
#pragma unroll
  for (int i = 0; i < 32; i += 8)
    t[ty + i][tx] = src[(size_t)(r0 + ty + i) * C + c0 + tx];
  __syncthreads();
#pragma unroll
  for (int i = 0; i < 32; i += 8)
    dst[(size_t)(c0 + ty + i) * R + r0 + tx] = f2us(t[tx][ty + i]);
}

// LayerNorm over last dim (256), bf16 out. One wave per row, 4 rows/block.
__global__ __launch_bounds__(256) void ln_kernel(
    const float* __restrict__ x, const float* __restrict__ g,
    const float* __restrict__ b, __hip_bfloat16* __restrict__ y)
{
  const int wid = threadIdx.x >> 6, lane = threadIdx.x & 63;
  const int row = blockIdx.x * 4 + wid;
  const float* xr = x + (size_t)row * DIMC;
  float v[4];
  float s = 0.f;
#pragma unroll
  for (int i = 0; i < 4; i++) { v[i] = xr[lane + 64*i]; s += v[i]; }
#pragma unroll
  for (int off = 32; off; off >>= 1) s += __shfl_xor(s, off);
  const float mu = s * (1.0f/256.0f);
  float var = 0.f;
#pragma unroll
  for (int i = 0; i < 4; i++) { const float d = v[i] - mu; var += d*d; }
#pragma unroll
  for (int off = 32; off; off >>= 1) var += __shfl_xor(var, off);
  const float rstd = rsqrtf(var * (1.0f/256.0f) + 1e-5f);
  __hip_bfloat16* yr = y + (size_t)row * DIMC;
#pragma unroll
  for (int i = 0; i < 4; i++) {
    const int c = lane + 64*i;
    yr[c] = __float2bfloat16((v[i] - mu) * rstd * g[c] + b[c]);
  }
}

// ---------------------------------------------------------------------------
// Fused FAVOR+ per (b,h): phase A (k-side, online-rescaled stab) computes
// ctx[m][d], ksum[m] entirely in LDS/registers; phase B (q-side) consumes
// them in the same block. 512 threads = 8 waves, static LDS 151,424 B.
// ---------------------------------------------------------------------------
__global__ __launch_bounds__(512) void favor_fused_kernel(
    const ushort* __restrict__ qn_all, const ushort* __restrict__ kn_all,
    const ushort* __restrict__ v_all, const ushort* __restrict__ projb,
    ushort* __restrict__ Ob)
{
  __shared__ __align__(16) uint8_t smem[151424];
  ushort (*kn_s)[72]      = (ushort(*)[72])(smem);            // [320][72] (qn in B)
  ushort (*vT_s)[328]     = (ushort(*)[328])(smem + 46080);   // [64][328] (ctxT in B)
  ushort (*proj_s)[72]    = (ushort(*)[72])(smem + 88064);    // [272][72]
  ushort (*kpT_s)[40]     = (ushort(*)[40])(smem + 127232);   // [272][40]
  ushort (*qp_s)[16][72]  = (ushort(*)[16][72])(smem + 127232); // [8][16][72] (B)
  float* diag_s = (float*)(smem + 148992);                    // [320]
  float* ksum_s = (float*)(smem + 150272);                    // [272]
  float* red_s  = (float*)(smem + 151360);                    // [8]

  const int tid = threadIdx.x, w = tid >> 6, lane = tid & 63;
  const int bh = blockIdx.x;
  const int b = bh >> 2, h = bh & 3;
  const int r = lane & 15, quad = lane >> 4;
  const int rl = lane >> 3, c8 = lane & 7;

  // ---------------- phase A staging ----------------
  {
    const ushort* knb = kn_all + (size_t)bh * 19200;
    for (int row = w*8 + rl; row < 320; row += 64) {
      uint4 u = {0u,0u,0u,0u};
      if (row < 300) u = *(const uint4*)(knb + row*64 + c8*8);
      *(uint4*)&kn_s[row][c8*8] = u;
      float s = sq8(u);
      s += __shfl_xor(s, 1); s += __shfl_xor(s, 2); s += __shfl_xor(s, 4);
      if (c8 == 0) diag_s[row] = 0.5f * s;
    }
    const ushort* vb = v_all + (size_t)bh * 19200;
    for (int row = w*8 + rl; row < 328; row += 64) {
      uint4 u = {0u,0u,0u,0u};
      if (row < 300) u = *(const uint4*)(vb + row*64 + c8*8);
      const unsigned int uu[4] = {u.x, u.y, u.z, u.w};
#pragma unroll
      for (int p = 0; p < 4; p++) {
        vT_s[c8*8 + 2*p    ][row] = (ushort)(uu[p] & 0xffff);
        vT_s[c8*8 + 2*p + 1][row] = (ushort)(uu[p] >> 16);
      }
    }
    for (int row = w*8 + rl; row < 272; row += 64) {
      uint4 u = {0u,0u,0u,0u};
      if (row < 266) u = *(const uint4*)(projb + row*64 + c8*8);
      *(uint4*)&proj_s[row][c8*8] = u;
    }
  }
  __syncthreads();

  // ---------------- phase A: online chunks of 32 n ----------------
  f32x4 cacc[9];
#pragma unroll
  for (int i = 0; i < 9; i++) cacc[i] = (f32x4){0.f,0.f,0.f,0.f};
  float ksum_acc = 0.f;
  float stab = -3.0e38f;

  for (int c = 0; c < 10; c++) {
    // dd tiles owned by this wave (<=5), chunk-local max
    f32x4 ddreg[5];
    float cmax = -3.0e38f;
#pragma unroll
    for (int ii = 0; ii < 5; ii++) {
      const int t = w + ii*8;
      if (t < 34) {
        const int tm = t >> 1, tn = c*2 + (t & 1);
        const bf16x8 a0 = *(const bf16x8*)&proj_s[tm*16 + r][quad*8];
        const bf16x8 a1 = *(const bf16x8*)&proj_s[tm*16 + r][32 + quad*8];
        const bf16x8 b0 = *(const bf16x8*)&kn_s[tn*16 + r][quad*8];
        const bf16x8 b1 = *(const bf16x8*)&kn_s[tn*16 + r][32 + quad*8];
        f32x4 acc = (f32x4){0.f,0.f,0.f,0.f};
        acc = MFMA16(a0, b0, acc);
        acc = MFMA16(a1, b1, acc);
        ddreg[ii] = acc;
        const int n = tn*16 + r;
        if (n < 300) {
#pragma unroll
          for (int j = 0; j < 4; j++) {
            const int m = tm*16 + quad*4 + j;
            if (m < 266) cmax = fmaxf(cmax, acc[j]);
          }
        }
      }
    }
#pragma unroll
    for (int off = 32; off; off >>= 1) cmax = fmaxf(cmax, __shfl_xor(cmax, off));
    if (lane == 0) red_s[w] = cmax;
    __syncthreads();
    float bmax = red_s[0];
#pragma unroll
    for (int i = 1; i < 8; i++) bmax = fmaxf(bmax, red_s[i]);
    const float stab_new = fmaxf(stab, bmax);
    const float alpha = __expf(stab - stab_new);   // chunk 0: exp(-inf)=0
    stab = stab_new;
    ksum_acc *= alpha;
#pragma unroll
    for (int i = 0; i < 9; i++)
#pragma unroll
      for (int j = 0; j < 4; j++) cacc[i][j] *= alpha;
    // kp = exp(dd - diag - stab) + eps (valid), else 0 -> kpT_s
#pragma unroll
    for (int ii = 0; ii < 5; ii++) {
      const int t = w + ii*8;
      if (t < 34) {
        const int tm = t >> 1, tnl = t & 1, tn = c*2 + tnl;
        const int n = tn*16 + r;
        const float dgn = diag_s[n];
#pragma unroll
        for (int j = 0; j < 4; j++) {
          const int m = tm*16 + quad*4 + j;
          float kp = 0.f;
          if (n < 300 && m < 266) kp = __expf(ddreg[ii][j] - dgn - stab) + KEPS;
          kpT_s[m][tnl*16 + r] = f2us(kp);
        }
      }
    }
    __syncthreads();
    // ksum row-sums + ctx MFMA accumulate
    if (tid < 272) {
      float rs = 0.f;
#pragma unroll
      for (int kk = 0; kk < 4; kk++) {
        const uint4 u = *(const uint4*)&kpT_s[tid][kk*8];
        const unsigned int uu[4] = {u.x, u.y, u.z, u.w};
#pragma unroll
        for (int p = 0; p < 4; p++)
          rs += bfbits2f((ushort)(uu[p] & 0xffff)) + bfbits2f((ushort)(uu[p] >> 16));
      }
      ksum_acc += rs;
    }
#pragma unroll
    for (int ii = 0; ii < 9; ii++) {
      const int t2 = w + ii*8;
      if (t2 < 68) {
        const int tm = t2 >> 2, td = t2 & 3;
        const bf16x8 aa = *(const bf16x8*)&kpT_s[tm*16 + r][quad*8];
        const bf16x8 bb = *(const bf16x8*)&vT_s[td*16 + r][c*32 + quad*8];
        cacc[ii] = MFMA16(aa, bb, cacc[ii]);
      }
    }
    __syncthreads();
  }

  // ---------------- A->B transition ----------------
  if (tid < 272) ksum_s[tid] = ksum_acc;
  // ctxT overlays vT (stride 328); cols m>=272 hold stale-but-finite bytes,
  // multiplied by explicit qp zeros in phase B.
#pragma unroll
  for (int ii = 0; ii < 9; ii++) {
    const int t2 = w + ii*8;
    if (t2 < 68) {
      const int tm = t2 >> 2, td = t2 & 3;
#pragma unroll
      for (int j = 0; j < 4; j++) {
        const int m = tm*16 + quad*4 + j;
        vT_s[td*16 + r][m] = f2us(cacc[ii][j]);   // ctxT[d][m]
      }
    }
  }
  // stage qn over kn_s (+ diag)
  {
    const ushort* qb = qn_all + (size_t)bh * 19200;
    for (int row = w*8 + rl; row < 320; row += 64) {
      uint4 u = {0u,0u,0u,0u};
      if (row < 300) u = *(const uint4*)(qb + row*64 + c8*8);
      *(uint4*)&kn_s[row][c8*8] = u;
      float s = sq8(u);
      s += __shfl_xor(s, 1); s += __shfl_xor(s, 2); s += __shfl_xor(s, 4);
      if (c8 == 0) diag_s[row] = 0.5f * s;
    }
  }
  __syncthreads();

  // ---------------- phase B: q-side ----------------
  for (int t = w; t < 19; t += 8) {
    const bf16x8 a0 = *(const bf16x8*)&kn_s[t*16 + r][quad*8];
    const bf16x8 a1 = *(const bf16x8*)&kn_s[t*16 + r][32 + quad*8];
    f32x4 dd[17];
#pragma unroll
    for (int tm = 0; tm < 17; tm++) {
      const bf16x8 b0 = *(const bf16x8*)&proj_s[tm*16 + r][quad*8];
      const bf16x8 b1 = *(const bf16x8*)&proj_s[tm*16 + r][32 + quad*8];
      f32x4 acc = (f32x4){0.f,0.f,0.f,0.f};
      acc = MFMA16(a0, b0, acc);
      acc = MFMA16(a1, b1, acc);
      dd[tm] = acc;
    }
    float mxj[4] = {-3.0e38f, -3.0e38f, -3.0e38f, -3.0e38f};
#pragma unroll
    for (int tm = 0; tm < 17; tm++) {
      if (tm*16 + r < 266) {
#pragma unroll
        for (int j = 0; j < 4; j++) mxj[j] = fmaxf(mxj[j], dd[tm][j]);
      }
    }
#pragma unroll
    for (int off = 1; off < 16; off <<= 1)
#pragma unroll
      for (int j = 0; j < 4; j++) mxj[j] = fmaxf(mxj[j], __shfl_xor(mxj[j], off));
    float dg[4];
#pragma unroll
    for (int j = 0; j < 4; j++) dg[j] = diag_s[t*16 + quad*4 + j];
    float den[4] = {0.f, 0.f, 0.f, 0.f};
#pragma unroll
    for (int tm = 0; tm < 17; tm++) {
      const float ks = ksum_s[tm*16 + r];
      const bool mval = (tm*16 + r < 266);
#pragma unroll
      for (int j = 0; j < 4; j++) {
        const int n = t*16 + quad*4 + j;
        float qp = 0.f;
        if (mval && n < 300) qp = __expf(dd[tm][j] - dg[j] - mxj[j]) + KEPS;
        dd[tm][j] = qp;
        den[j] += qp * ks;
      }
    }
#pragma unroll
    for (int off = 1; off < 16; off <<= 1)
#pragma unroll
      for (int j = 0; j < 4; j++) den[j] += __shfl_xor(den[j], off);
    float dinv[4];
#pragma unroll
    for (int j = 0; j < 4; j++) dinv[j] = 1.0f / den[j];

    // o = qp @ ctxT, K = 320 in 5 groups of 64 (tm>=17 zero)
    f32x4 oacc[4];
#pragma unroll
    for (int td = 0; td < 4; td++) oacc[td] = (f32x4){0.f,0.f,0.f,0.f};
#pragma unroll
    for (int g = 0; g < 5; g++) {
#pragma unroll
      for (int tt = 0; tt < 4; tt++) {
        const int tm = g*4 + tt;
#pragma unroll
        for (int j = 0; j < 4; j++) {
          const ushort us = (tm <= 16) ? f2us(dd[tm][j]) : (ushort)0;
          qp_s[w][quad*4 + j][tt*16 + r] = us;
        }
      }
#pragma unroll
      for (int s = 0; s < 2; s++) {
        const bf16x8 aa = *(const bf16x8*)&qp_s[w][r][s*32 + quad*8];
#pragma unroll
        for (int td = 0; td < 4; td++) {
          const bf16x8 bb = *(const bf16x8*)&vT_s[td*16 + r][g*64 + s*32 + quad*8];
          oacc[td] = MFMA16(aa, bb, oacc[td]);
        }
      }
    }
#pragma unroll
    for (int td = 0; td < 4; td++) {
#pragma unroll
      for (int j = 0; j < 4; j++) {
        const int n = t*16 + quad*4 + j;
        if (n < 300)
          Ob[((size_t)b*300 + n)*256 + h*64 + td*16 + r] = f2us(oacc[td][j] * dinv[j]);
      }
    }
  }
}

// ---------------------------------------------------------------------------
// Mean-pool over N, LayerNorm, 256->128 ReLU, 128->1 sigmoid. Block per batch.
// ---------------------------------------------------------------------------
__global__ __launch_bounds__(256) void head_kernel(
    const float* __restrict__ h, const float* __restrict__ hg,
    const float* __restrict__ hb, const float* __restrict__ wh1,
    const float* __restrict__ bh1, const float* __restrict__ wh2,
    const float* __restrict__ bh2, float* __restrict__ out)
{
  __shared__ float z_s[256];
  __shared__ float hid_s[128];
  __shared__ float red_s[4];
  const int b = blockIdx.x, tid = threadIdx.x;
  const float* hb_ = h + (size_t)b * NSEQ * DIMC;
  float s = 0.f;
  for (int n = 0; n < NSEQ; n++) s += hb_[(size_t)n * DIMC + tid];
  s *= (1.0f / 300.0f);
  float t1 = s;
#pragma unroll
  for (int off = 32; off; off >>= 1) t1 += __shfl_xor(t1, off);
  if ((tid & 63) == 0) red_s[tid >> 6] = t1;
  __syncthreads();
  const float mu = (red_s[0] + red_s[1] + red_s[2] + red_s[3]) * (1.0f/256.0f);
  __syncthreads();
  const float d = s - mu;
  float vv = d * d;
#pragma unroll
  for (int off = 32; off; off >>= 1) vv += __shfl_xor(vv, off);
  if ((tid & 63) == 0) red_s[tid >> 6] = vv;
  __syncthreads();
  const float var = (red_s[0] + red_s[1] + red_s[2] + red_s[3]) * (1.0f/256.0f);
  z_s[tid] = d * rsqrtf(var + 1e-5f) * hg[tid] + hb[tid];
  __syncthreads();
  if (tid < 128) {
    float acc = bh1[tid];
    for (int dd = 0; dd < 256; dd++) acc += z_s[dd] * wh1[dd * 128 + tid];
    hid_s[tid] = fmaxf(acc, 0.f);
  }
  __syncthreads();
  if (tid < 64) {
    float acc = hid_s[tid] * wh2[tid] + hid_s[tid + 64] * wh2[tid + 64];
#pragma unroll
    for (int off = 32; off; off >>= 1) acc += __shfl_xor(acc, off);
    if (tid == 0) {
      const float val = acc + bh2[0];
      out[b] = 1.0f / (1.0f + __expf(-val));
    }
  }
}

// ---------------------------------------------------------------------------
extern "C" void kernel_launch(void* const* d_in, const int* in_sizes, int n_in,
                              void* d_out, int out_size, void* d_ws, size_t ws_size,
                              hipStream_t stream) {
  const float* x    = (const float*)d_in[0];
  const float* w_in = (const float*)d_in[1];
  const float* b_in = (const float*)d_in[2];
  const float* proj = (const float*)d_in[3];
  const float* ln1g = (const float*)d_in[4];
  const float* ln1b = (const float*)d_in[5];
  const float* wq   = (const float*)d_in[6];
  const float* wk   = (const float*)d_in[7];
  const float* wv   = (const float*)d_in[8];
  const float* wo   = (const float*)d_in[9];
  const float* bo   = (const float*)d_in[10];
  const float* ln2g = (const float*)d_in[11];
  const float* ln2b = (const float*)d_in[12];
  const float* w1   = (const float*)d_in[13];
  const float* b1   = (const float*)d_in[14];
  const float* w2   = (const float*)d_in[15];
  const float* b2   = (const float*)d_in[16];
  const float* hg   = (const float*)d_in[17];
  const float* hbp  = (const float*)d_in[18];
  const float* wh1  = (const float*)d_in[19];
  const float* bh1  = (const float*)d_in[20];
  const float* wh2  = (const float*)d_in[21];
  const float* bh2  = (const float*)d_in[22];

  uint8_t* base = (uint8_t*)d_ws;
  float*  h     = (float*)(base);                        // 78,643,200 B
  ushort* yb    = (ushort*)(base + 78643200);            // 39,321,600 B
  ushort* qkv   = (ushort*)(base + 117964800);           // 117,964,800 B
  ushort* ob    = (ushort*)(base + 235929600);           // 39,321,600 B
  ushort* wbuf  = (ushort*)(base + 275251200);           //  3,801,088 B
  ushort* projb = (ushort*)(base + 279052288);           //     68,096 B
  // aliases (disjoint lifetimes):
  ushort* tb = qkv;                      // FFN hidden [76800][1024] over qkv+ob
  ushort* qb = qkv;
  ushort* kb = qkv + 19660800;
  ushort* vb = qkv + 39321600;

  ushort* w_inT = wbuf;                  // [256][1280]
  ushort* wT0   = wbuf + 327680;

  // --- prep: proj cast + all 13 weight transposes in one launch ---
  cast_bf16_kernel<<<34, 256, 0, stream>>>(proj, projb, 8512);
  TTab tab;
  int nb = 0;
  auto add = [&](const float* s, ushort* d, int R, int C) {
    tab.s[nb % 13] = TSeg{s, d, R, C, 0};
  };
  {
    int idx = 0, basem = 0;
    auto seg = [&](const float* s, ushort* d, int R, int C) {
      tab.s[idx] = TSeg{s, d, R, C, basem};
      basem += (R >> 5) * (C >> 5);
      idx++;
    };
    seg(w_in, w_inT, 1280, 256);
    for (int l = 0; l < 2; l++) {
      ushort* wl = wT0 + (size_t)l * 786432;
      seg(wq + (size_t)l*65536,  wl,          256, 256);
      seg(wk + (size_t)l*65536,  wl + 65536,  256, 256);
      seg(wv + (size_t)l*65536,  wl + 131072, 256, 256);
      seg(wo + (size_t)l*65536,  wl + 196608, 256, 256);
      seg(w1 + (size_t)l*262144, wl + 262144, 256, 1024);
      seg(w2 + (size_t)l*262144, wl + 524288, 1024, 256);
    }
    nb = basem;  // 1856
  }
  tcast_all<<<nb, 256, 0, stream>>>(tab);

  // --- h = x @ w_in + b_in (A read as fp32 directly) ---
  gemm_mfma<0,0,1><<<dim3(600, 2), 256, 0, stream>>>(
      nullptr, x, w_inT, b_in, nullptr, h, nullptr, nullptr, 76800, 256, 1280);

  for (int l = 0; l < 2; l++) {
    ushort* wl = wT0 + (size_t)l * 786432;
    ushort* projL = projb + (size_t)l * 17024;
    ln_kernel<<<19200, 256, 0, stream>>>(h, ln1g + l*256, ln1b + l*256, (__hip_bfloat16*)yb);
    gemm_mfma<4,0,0><<<dim3(600, 6), 256, 0, stream>>>(
        yb, nullptr, wl, nullptr, nullptr, nullptr, nullptr, qkv, 76800, 768, 256);
    favor_fused_kernel<<<1024, 512, 0, stream>>>(qb, kb, vb, projL, ob);
    gemm_mfma<1,0,0><<<dim3(600, 2), 256, 0, stream>>>(
        ob, nullptr, wl + 196608, bo + l*256, h, h, nullptr, nullptr, 76800, 256, 256);
    ln_kernel<<<19200, 256, 0, stream>>>(h, ln2g + l*256, ln2b + l*256, (__hip_bfloat16*)yb);
    gemm_mfma<2,1,0><<<dim3(600, 8), 256, 0, stream>>>(
        yb, nullptr, wl + 262144, b1 + l*1024, nullptr, nullptr, (__hip_bfloat16*)tb, nullptr, 76800, 1024, 256);
    gemm_mfma<1,0,0><<<dim3(600, 2), 256, 0, stream>>>(
        tb, nullptr, wl + 524288, b2 + l*256, h, h, nullptr, nullptr, 76800, 256, 1024);
  }
  head_kernel<<<256, 256, 0, stream>>>(h, hg, hbp, wh1, bh1, wh2, bh2, (float*)d_out);
}